// Round 1
// baseline (4372.509 us; speedup 1.0000x reference)
//
#include <hip/hip_runtime.h>
#include <hip/hip_bf16.h>
#include <stdint.h>

#define HID  4096
#define INTR 14336
#define GS   64
#define TOK  4096
#define GRP1 (HID / GS)    // 64 groups along K for w1/w3
#define GRP2 (INTR / GS)   // 224 groups along K for w2

#define BM 256
#define BN 128
#define BK 64

typedef __attribute__((ext_vector_type(8))) short short8;  // 8 bf16 (4 VGPR)
typedef __attribute__((ext_vector_type(4))) float f32x4;   // MFMA acc
typedef unsigned short u16;
typedef unsigned int   u32;

// ---- helpers -------------------------------------------------------------

__device__ __forceinline__ u16 f2b(float x) {
    return __builtin_bit_cast(u16, __float2bfloat16(x));
}

__device__ __forceinline__ u32 pk2(float a, float b) {
    return (u32)f2b(a) | ((u32)f2b(b) << 16);
}

// dequant two int codes -> packed bf16 pair;  w = c*s + off  (off = -zero*s)
__device__ __forceinline__ u32 dq2(int ca, int cb, float s, float off) {
    return pk2(fmaf((float)ca, s, off), fmaf((float)cb, s, off));
}

// ---- kernel 1: hs fp32 -> bf16 -------------------------------------------

__global__ void cvt_hs_kernel(const float* __restrict__ x, u16* __restrict__ y) {
    int i = blockIdx.x * blockDim.x + threadIdx.x;   // 8 elems per thread
    const float4* xp = (const float4*)x + (size_t)i * 2;
    float4 a = xp[0], b = xp[1];
    uint4 o;
    o.x = pk2(a.x, a.y); o.y = pk2(a.z, a.w);
    o.z = pk2(b.x, b.y); o.w = pk2(b.z, b.w);
    ((uint4*)y)[i] = o;
}

// ---- kernel 2: fused gate+up dual GEMM + SiLU*mul -------------------------
// C1[t,i] = sum_h hs[t,h]*w1[i,h];  C3 same with w3;  h_out = silu(C1)*C3 (bf16)
// grid: (TOK/BM, INTR/BN); blockIdx.x fastest => blocks sharing the B panel
// are concurrent => weight codes stream from HBM ~once.

__global__ __launch_bounds__(512) void gateup_kernel(
    const u16* __restrict__ hsb,
    const int* __restrict__ w1q, const float* __restrict__ s1, const float* __restrict__ z1,
    const int* __restrict__ w3q, const float* __restrict__ s3, const float* __restrict__ z3,
    u16* __restrict__ hout)
{
    __shared__ u16 sA [BM * BK];   // 32 KB, [256][64] row-major, chunk-swizzled
    __shared__ u16 sB1[BN * BK];   // 16 KB, [128][64]
    __shared__ u16 sB3[BN * BK];   // 16 KB

    const int tid  = threadIdx.x;
    const int row0 = blockIdx.x * BM;
    const int col0 = blockIdx.y * BN;

    const int l   = tid & 63;
    const int wid = tid >> 6;      // 0..7
    const int wr  = wid >> 1;      // 0..3 (M)
    const int wc  = wid & 1;       // 0..1 (N)
    const int fq  = l >> 4;        // 0..3
    const int fr  = l & 15;        // 0..15

    f32x4 accg[4][4];
    f32x4 accu[4][4];
#pragma unroll
    for (int m = 0; m < 4; ++m)
#pragma unroll
        for (int n = 0; n < 4; ++n) {
            accg[m][n] = (f32x4){0.f, 0.f, 0.f, 0.f};
            accu[m][n] = (f32x4){0.f, 0.f, 0.f, 0.f};
        }

    // staging decomposition
    const int ar  = tid >> 3;           // A: row within 64-row chunk (8 thr/row)
    const int ac  = tid & 7;            // A: 16B chunk index 0..7
    const int br  = tid >> 2;           // B: row 0..127 (4 thr/row)
    const int bc0 = (tid & 3) << 1;     // B: chunk base 0,2,4,6
    const int r7  = br & 7;

    const size_t aBase = (size_t)(row0 + ar) * HID + (ac << 3);
    const int* p1 = w1q + (size_t)(col0 + br) * HID + ((tid & 3) << 4);
    const int* p3 = w3q + (size_t)(col0 + br) * HID + ((tid & 3) << 4);
    const size_t sBase = (size_t)(col0 + br) * GRP1;

    for (int ks = 0; ks < HID / BK; ++ks) {
        const int k0 = ks * BK;

        // -- global loads into regs (latency overlaps previous MFMA tail) --
        uint4 av[4];
#pragma unroll
        for (int it = 0; it < 4; ++it)
            av[it] = *(const uint4*)(hsb + aBase + (size_t)(it * 64) * HID + k0);
        int4 c1[4], c3[4];
#pragma unroll
        for (int j = 0; j < 4; ++j) c1[j] = *(const int4*)(p1 + k0 + j * 4);
#pragma unroll
        for (int j = 0; j < 4; ++j) c3[j] = *(const int4*)(p3 + k0 + j * 4);
        const float sc1 = s1[sBase + ks];
        const float of1 = -z1[sBase + ks] * sc1;
        const float sc3 = s3[sBase + ks];
        const float of3 = -z3[sBase + ks] * sc3;

        __syncthreads();   // previous compute finished reading LDS

        // -- LDS writes (XOR chunk swizzle: chunk ^= row&7) --
#pragma unroll
        for (int it = 0; it < 4; ++it) {
            int row = it * 64 + ar;
            *(uint4*)(&sA[row * BK + ((ac ^ (row & 7)) << 3)]) = av[it];
        }
        {
            uint4 lo, hi;
            lo.x = dq2(c1[0].x, c1[0].y, sc1, of1);
            lo.y = dq2(c1[0].z, c1[0].w, sc1, of1);
            lo.z = dq2(c1[1].x, c1[1].y, sc1, of1);
            lo.w = dq2(c1[1].z, c1[1].w, sc1, of1);
            hi.x = dq2(c1[2].x, c1[2].y, sc1, of1);
            hi.y = dq2(c1[2].z, c1[2].w, sc1, of1);
            hi.z = dq2(c1[3].x, c1[3].y, sc1, of1);
            hi.w = dq2(c1[3].z, c1[3].w, sc1, of1);
            *(uint4*)(&sB1[br * BK + (( bc0      ^ r7) << 3)]) = lo;
            *(uint4*)(&sB1[br * BK + (((bc0 + 1) ^ r7) << 3)]) = hi;
            lo.x = dq2(c3[0].x, c3[0].y, sc3, of3);
            lo.y = dq2(c3[0].z, c3[0].w, sc3, of3);
            lo.z = dq2(c3[1].x, c3[1].y, sc3, of3);
            lo.w = dq2(c3[1].z, c3[1].w, sc3, of3);
            hi.x = dq2(c3[2].x, c3[2].y, sc3, of3);
            hi.y = dq2(c3[2].z, c3[2].w, sc3, of3);
            hi.z = dq2(c3[3].x, c3[3].y, sc3, of3);
            hi.w = dq2(c3[3].z, c3[3].w, sc3, of3);
            *(uint4*)(&sB3[br * BK + (( bc0      ^ r7) << 3)]) = lo;
            *(uint4*)(&sB3[br * BK + (((bc0 + 1) ^ r7) << 3)]) = hi;
        }
        __syncthreads();

        // -- MFMA --
#pragma unroll
        for (int kk = 0; kk < 2; ++kk) {
            short8 af[4], b1f[4], b3f[4];
#pragma unroll
            for (int m = 0; m < 4; ++m) {
                int row = wr * 64 + m * 16 + fr;
                af[m] = *(const short8*)(&sA[row * BK + ((((kk << 2) | fq) ^ (row & 7)) << 3)]);
            }
#pragma unroll
            for (int n = 0; n < 4; ++n) {
                int row = wc * 64 + n * 16 + fr;
                int ch  = (((kk << 2) | fq) ^ (row & 7)) << 3;
                b1f[n] = *(const short8*)(&sB1[row * BK + ch]);
                b3f[n] = *(const short8*)(&sB3[row * BK + ch]);
            }
#pragma unroll
            for (int m = 0; m < 4; ++m)
#pragma unroll
                for (int n = 0; n < 4; ++n) {
                    accg[m][n] = __builtin_amdgcn_mfma_f32_16x16x32_bf16(af[m], b1f[n], accg[m][n], 0, 0, 0);
                    accu[m][n] = __builtin_amdgcn_mfma_f32_16x16x32_bf16(af[m], b3f[n], accu[m][n], 0, 0, 0);
                }
        }
    }

    // -- epilogue: h = silu(g)*u, bf16 --
#pragma unroll
    for (int m = 0; m < 4; ++m)
#pragma unroll
        for (int n = 0; n < 4; ++n)
#pragma unroll
            for (int r = 0; r < 4; ++r) {
                int t = row0 + wr * 64 + m * 16 + fq * 4 + r;
                int i = col0 + wc * 64 + n * 16 + fr;
                float g = accg[m][n][r];
                float u = accu[m][n][r];
                float hv = (g / (1.0f + __expf(-g))) * u;
                hout[(size_t)t * INTR + i] = f2b(hv);
            }
}

// ---- kernel 3: down proj --------------------------------------------------
// out[t,h] = sum_i hmid[t,i] * w2[h,i]   (fp32 out)

__global__ __launch_bounds__(512) void down_kernel(
    const u16* __restrict__ hb,
    const int* __restrict__ w2q, const float* __restrict__ s2, const float* __restrict__ z2,
    float* __restrict__ out)
{
    __shared__ u16 sA[BM * BK];   // 32 KB
    __shared__ u16 sB[BN * BK];   // 16 KB

    const int tid  = threadIdx.x;
    const int row0 = blockIdx.x * BM;
    const int col0 = blockIdx.y * BN;

    const int l   = tid & 63;
    const int wid = tid >> 6;
    const int wr  = wid >> 1;
    const int wc  = wid & 1;
    const int fq  = l >> 4;
    const int fr  = l & 15;

    f32x4 acc[4][4];
#pragma unroll
    for (int m = 0; m < 4; ++m)
#pragma unroll
        for (int n = 0; n < 4; ++n)
            acc[m][n] = (f32x4){0.f, 0.f, 0.f, 0.f};

    const int ar  = tid >> 3;
    const int ac  = tid & 7;
    const int br  = tid >> 2;
    const int bc0 = (tid & 3) << 1;
    const int r7  = br & 7;

    const size_t aBase = (size_t)(row0 + ar) * INTR + (ac << 3);
    const int* p2 = w2q + (size_t)(col0 + br) * INTR + ((tid & 3) << 4);
    const size_t sBase = (size_t)(col0 + br) * GRP2;

    for (int ks = 0; ks < INTR / BK; ++ks) {
        const int k0 = ks * BK;

        uint4 av[4];
#pragma unroll
        for (int it = 0; it < 4; ++it)
            av[it] = *(const uint4*)(hb + aBase + (size_t)(it * 64) * INTR + k0);
        int4 c2[4];
#pragma unroll
        for (int j = 0; j < 4; ++j) c2[j] = *(const int4*)(p2 + k0 + j * 4);
        const float sc = s2[sBase + ks];
        const float of = -z2[sBase + ks] * sc;

        __syncthreads();

#pragma unroll
        for (int it = 0; it < 4; ++it) {
            int row = it * 64 + ar;
            *(uint4*)(&sA[row * BK + ((ac ^ (row & 7)) << 3)]) = av[it];
        }
        {
            uint4 lo, hi;
            lo.x = dq2(c2[0].x, c2[0].y, sc, of);
            lo.y = dq2(c2[0].z, c2[0].w, sc, of);
            lo.z = dq2(c2[1].x, c2[1].y, sc, of);
            lo.w = dq2(c2[1].z, c2[1].w, sc, of);
            hi.x = dq2(c2[2].x, c2[2].y, sc, of);
            hi.y = dq2(c2[2].z, c2[2].w, sc, of);
            hi.z = dq2(c2[3].x, c2[3].y, sc, of);
            hi.w = dq2(c2[3].z, c2[3].w, sc, of);
            *(uint4*)(&sB[br * BK + (( bc0      ^ r7) << 3)]) = lo;
            *(uint4*)(&sB[br * BK + (((bc0 + 1) ^ r7) << 3)]) = hi;
        }
        __syncthreads();

#pragma unroll
        for (int kk = 0; kk < 2; ++kk) {
            short8 af[4], bf[4];
#pragma unroll
            for (int m = 0; m < 4; ++m) {
                int row = wr * 64 + m * 16 + fr;
                af[m] = *(const short8*)(&sA[row * BK + ((((kk << 2) | fq) ^ (row & 7)) << 3)]);
            }
#pragma unroll
            for (int n = 0; n < 4; ++n) {
                int row = wc * 64 + n * 16 + fr;
                bf[n] = *(const short8*)(&sB[row * BK + ((((kk << 2) | fq) ^ (row & 7)) << 3)]);
            }
#pragma unroll
            for (int m = 0; m < 4; ++m)
#pragma unroll
                for (int n = 0; n < 4; ++n)
                    acc[m][n] = __builtin_amdgcn_mfma_f32_16x16x32_bf16(af[m], bf[n], acc[m][n], 0, 0, 0);
        }
    }

#pragma unroll
    for (int m = 0; m < 4; ++m)
#pragma unroll
        for (int n = 0; n < 4; ++n)
#pragma unroll
            for (int r = 0; r < 4; ++r) {
                int t = row0 + wr * 64 + m * 16 + fq * 4 + r;
                int i = col0 + wc * 64 + n * 16 + fr;
                out[(size_t)t * HID + i] = acc[m][n][r];
            }
}

// ---- launcher --------------------------------------------------------------

extern "C" void kernel_launch(void* const* d_in, const int* in_sizes, int n_in,
                              void* d_out, int out_size, void* d_ws, size_t ws_size,
                              hipStream_t stream) {
    (void)in_sizes; (void)n_in; (void)out_size; (void)ws_size;

    const float* hs  = (const float*)d_in[0];
    const int*   w1q = (const int*)  d_in[1];
    const float* w1s = (const float*)d_in[2];
    const float* w1z = (const float*)d_in[3];
    const int*   w3q = (const int*)  d_in[4];
    const float* w3s = (const float*)d_in[5];
    const float* w3z = (const float*)d_in[6];
    const int*   w2q = (const int*)  d_in[7];
    const float* w2s = (const float*)d_in[8];
    const float* w2z = (const float*)d_in[9];
    float* out = (float*)d_out;

    u16* hsb  = (u16*)d_ws;                       // [TOK][HID]  bf16 (32 MB)
    u16* hmid = hsb + (size_t)TOK * HID;          // [TOK][INTR] bf16 (117 MB)

    // 1. convert hidden states to bf16
    cvt_hs_kernel<<<(TOK * HID / 8) / 256, 256, 0, stream>>>(hs, hsb);

    // 2. gate+up fused dual GEMM + SwiGLU
    dim3 g2(TOK / BM, INTR / BN);   // x fastest: blocks sharing B panel adjacent
    gateup_kernel<<<g2, 512, 0, stream>>>(hsb, w1q, w1s, w1z, w3q, w3s, w3z, hmid);

    // 3. down projection
    dim3 g3(TOK / BM, HID / BN);
    down_kernel<<<g3, 512, 0, stream>>>(hmid, w2q, w2s, w2z, out);
}

// Round 2
// 4236.967 us; speedup vs baseline: 1.0320x; 1.0320x over previous
//
#include <hip/hip_runtime.h>
#include <hip/hip_bf16.h>
#include <stdint.h>

#define HID  4096
#define INTR 14336
#define GS   64
#define TOK  4096
#define GRP1 (HID / GS)    // 64 groups along K for w1/w3
#define GRP2 (INTR / GS)   // 224 groups along K for w2

#define BM 256
#define BN 128
#define BK 64

typedef __attribute__((ext_vector_type(8))) short short8;  // 8 bf16 (4 VGPR)
typedef __attribute__((ext_vector_type(4))) float f32x4;   // MFMA acc
typedef unsigned short u16;
typedef unsigned int   u32;

// ---- helpers -------------------------------------------------------------

__device__ __forceinline__ u16 f2b(float x) {
    return __builtin_bit_cast(u16, __float2bfloat16(x));
}

__device__ __forceinline__ u32 pk2(float a, float b) {
    return (u32)f2b(a) | ((u32)f2b(b) << 16);
}

// dequant two int codes -> packed bf16 pair;  w = c*s + off  (off = -zero*s)
__device__ __forceinline__ u32 dq2(int ca, int cb, float s, float off) {
    return pk2(fmaf((float)ca, s, off), fmaf((float)cb, s, off));
}

// ---- kernel 1: hs fp32 -> bf16 -------------------------------------------

__global__ void cvt_hs_kernel(const float* __restrict__ x, u16* __restrict__ y) {
    int i = blockIdx.x * blockDim.x + threadIdx.x;   // 8 elems per thread
    const float4* xp = (const float4*)x + (size_t)i * 2;
    float4 a = xp[0], b = xp[1];
    uint4 o;
    o.x = pk2(a.x, a.y); o.y = pk2(a.z, a.w);
    o.z = pk2(b.x, b.y); o.w = pk2(b.z, b.w);
    ((uint4*)y)[i] = o;
}

// ---- kernel 2: fused gate+up dual GEMM + SiLU*mul -------------------------
// Register-prefetch pipeline: dequant+LDS-write tile k (from regs), barrier,
// issue loads for k+1, MFMA tile k (loads land underneath), barrier.

__global__ __launch_bounds__(512) void gateup_kernel(
    const u16* __restrict__ hsb,
    const int* __restrict__ w1q, const float* __restrict__ s1, const float* __restrict__ z1,
    const int* __restrict__ w3q, const float* __restrict__ s3, const float* __restrict__ z3,
    u16* __restrict__ hout)
{
    __shared__ __align__(16) char smem[64 * 1024];
    u16* sA  = (u16*)smem;             // 32 KB [256][64] swizzled
    u16* sB1 = (u16*)(smem + 32768);   // 16 KB [128][64]
    u16* sB3 = (u16*)(smem + 49152);   // 16 KB

    const int tid  = threadIdx.x;
    const int row0 = blockIdx.x * BM;
    const int col0 = blockIdx.y * BN;

    const int l   = tid & 63;
    const int wid = tid >> 6;      // 0..7
    const int wr  = wid >> 1;      // 0..3 (M)
    const int wc  = wid & 1;       // 0..1 (N)
    const int fq  = l >> 4;        // 0..3
    const int fr  = l & 15;        // 0..15

    f32x4 accg[4][4];
    f32x4 accu[4][4];
#pragma unroll
    for (int m = 0; m < 4; ++m)
#pragma unroll
        for (int n = 0; n < 4; ++n) {
            accg[m][n] = (f32x4){0.f, 0.f, 0.f, 0.f};
            accu[m][n] = (f32x4){0.f, 0.f, 0.f, 0.f};
        }

    // staging decomposition
    const int ar  = tid >> 3;           // A: row within 64-row chunk
    const int ac  = tid & 7;            // A: 16B chunk index 0..7
    const int br  = tid >> 2;           // B: row 0..127
    const int bc0 = (tid & 3) << 1;     // B: chunk base 0,2,4,6
    const int r7  = br & 7;

    const size_t aBase = (size_t)(row0 + ar) * HID + (ac << 3);
    const int* p1 = w1q + (size_t)(col0 + br) * HID + ((tid & 3) << 4);
    const int* p3 = w3q + (size_t)(col0 + br) * HID + ((tid & 3) << 4);
    const size_t sBase = (size_t)(col0 + br) * GRP1;

    uint4 av[4];
    int4  c1[4], c3[4];
    float sc1, zz1, sc3, zz3;

#define GU_LOAD(KS) do {                                                        \
        const int k0_ = (KS) * BK;                                              \
        _Pragma("unroll")                                                       \
        for (int it = 0; it < 4; ++it)                                          \
            av[it] = *(const uint4*)(hsb + aBase + (size_t)(it * 64) * HID + k0_); \
        _Pragma("unroll")                                                       \
        for (int j = 0; j < 4; ++j) c1[j] = *(const int4*)(p1 + k0_ + j * 4);   \
        _Pragma("unroll")                                                       \
        for (int j = 0; j < 4; ++j) c3[j] = *(const int4*)(p3 + k0_ + j * 4);   \
        sc1 = s1[sBase + (KS)]; zz1 = z1[sBase + (KS)];                         \
        sc3 = s3[sBase + (KS)]; zz3 = z3[sBase + (KS)];                         \
    } while (0)

    GU_LOAD(0);

    for (int ks = 0; ks < HID / BK; ++ks) {
        // -- dequant + LDS write from regs (XOR chunk swizzle) --
        const float of1 = -zz1 * sc1;
        const float of3 = -zz3 * sc3;
#pragma unroll
        for (int it = 0; it < 4; ++it) {
            int row = it * 64 + ar;
            *(uint4*)(&sA[row * BK + ((ac ^ (row & 7)) << 3)]) = av[it];
        }
        {
            uint4 lo, hi;
            lo.x = dq2(c1[0].x, c1[0].y, sc1, of1);
            lo.y = dq2(c1[0].z, c1[0].w, sc1, of1);
            lo.z = dq2(c1[1].x, c1[1].y, sc1, of1);
            lo.w = dq2(c1[1].z, c1[1].w, sc1, of1);
            hi.x = dq2(c1[2].x, c1[2].y, sc1, of1);
            hi.y = dq2(c1[2].z, c1[2].w, sc1, of1);
            hi.z = dq2(c1[3].x, c1[3].y, sc1, of1);
            hi.w = dq2(c1[3].z, c1[3].w, sc1, of1);
            *(uint4*)(&sB1[br * BK + (( bc0      ^ r7) << 3)]) = lo;
            *(uint4*)(&sB1[br * BK + (((bc0 + 1) ^ r7) << 3)]) = hi;
            lo.x = dq2(c3[0].x, c3[0].y, sc3, of3);
            lo.y = dq2(c3[0].z, c3[0].w, sc3, of3);
            lo.z = dq2(c3[1].x, c3[1].y, sc3, of3);
            lo.w = dq2(c3[1].z, c3[1].w, sc3, of3);
            hi.x = dq2(c3[2].x, c3[2].y, sc3, of3);
            hi.y = dq2(c3[2].z, c3[2].w, sc3, of3);
            hi.z = dq2(c3[3].x, c3[3].y, sc3, of3);
            hi.w = dq2(c3[3].z, c3[3].w, sc3, of3);
            *(uint4*)(&sB3[br * BK + (( bc0      ^ r7) << 3)]) = lo;
            *(uint4*)(&sB3[br * BK + (((bc0 + 1) ^ r7) << 3)]) = hi;
        }
        __syncthreads();

        // -- issue next tile's loads; they complete under the MFMA below --
        if (ks + 1 < HID / BK) GU_LOAD(ks + 1);

        // -- MFMA --
#pragma unroll
        for (int kk = 0; kk < 2; ++kk) {
            short8 af[4], b1f[4], b3f[4];
#pragma unroll
            for (int m = 0; m < 4; ++m) {
                int row = wr * 64 + m * 16 + fr;
                af[m] = *(const short8*)(&sA[row * BK + ((((kk << 2) | fq) ^ (row & 7)) << 3)]);
            }
#pragma unroll
            for (int n = 0; n < 4; ++n) {
                int row = wc * 64 + n * 16 + fr;
                int ch  = (((kk << 2) | fq) ^ (row & 7)) << 3;
                b1f[n] = *(const short8*)(&sB1[row * BK + ch]);
                b3f[n] = *(const short8*)(&sB3[row * BK + ch]);
            }
#pragma unroll
            for (int m = 0; m < 4; ++m)
#pragma unroll
                for (int n = 0; n < 4; ++n) {
                    accg[m][n] = __builtin_amdgcn_mfma_f32_16x16x32_bf16(af[m], b1f[n], accg[m][n], 0, 0, 0);
                    accu[m][n] = __builtin_amdgcn_mfma_f32_16x16x32_bf16(af[m], b3f[n], accu[m][n], 0, 0, 0);
                }
        }
        __syncthreads();
    }
#undef GU_LOAD

    // -- epilogue: h = silu(g)*u -> LDS stage -> coalesced dwordx4 stores --
    u16* sO = (u16*)smem;    // [256][128] bf16 = 64 KB (K-loop LDS is free now)
#pragma unroll
    for (int m = 0; m < 4; ++m)
#pragma unroll
        for (int n = 0; n < 4; ++n)
#pragma unroll
            for (int r = 0; r < 4; ++r) {
                int lr = wr * 64 + m * 16 + fq * 4 + r;
                int lc = wc * 64 + n * 16 + fr;
                float g = accg[m][n][r];
                float u = accu[m][n][r];
                float hv = (g / (1.0f + __expf(-g))) * u;
                sO[lr * 128 + lc] = f2b(hv);
            }
    __syncthreads();
#pragma unroll
    for (int it = 0; it < 8; ++it) {
        int idx = it * 512 + tid;          // 16B units, 4096 total
        int row = idx >> 4;                // 256B per row
        int cu  = idx & 15;
        uint4 v = ((const uint4*)sO)[idx];
        *(uint4*)(&hout[(size_t)(row0 + row) * INTR + col0 + (cu << 3)]) = v;
    }
}

// ---- kernel 3: down proj --------------------------------------------------

__global__ __launch_bounds__(512) void down_kernel(
    const u16* __restrict__ hb,
    const int* __restrict__ w2q, const float* __restrict__ s2, const float* __restrict__ z2,
    float* __restrict__ out)
{
    __shared__ __align__(16) char smem[64 * 1024];
    u16* sA = (u16*)smem;              // 32 KB
    u16* sB = (u16*)(smem + 32768);    // 16 KB

    const int tid  = threadIdx.x;
    const int row0 = blockIdx.x * BM;
    const int col0 = blockIdx.y * BN;

    const int l   = tid & 63;
    const int wid = tid >> 6;
    const int wr  = wid >> 1;
    const int wc  = wid & 1;
    const int fq  = l >> 4;
    const int fr  = l & 15;

    f32x4 acc[4][4];
#pragma unroll
    for (int m = 0; m < 4; ++m)
#pragma unroll
        for (int n = 0; n < 4; ++n)
            acc[m][n] = (f32x4){0.f, 0.f, 0.f, 0.f};

    const int ar  = tid >> 3;
    const int ac  = tid & 7;
    const int br  = tid >> 2;
    const int bc0 = (tid & 3) << 1;
    const int r7  = br & 7;

    const size_t aBase = (size_t)(row0 + ar) * INTR + (ac << 3);
    const int* p2 = w2q + (size_t)(col0 + br) * INTR + ((tid & 3) << 4);
    const size_t sBase = (size_t)(col0 + br) * GRP2;

    uint4 av[4];
    int4  c2[4];
    float sc, zz;

#define DN_LOAD(KS) do {                                                        \
        const int k0_ = (KS) * BK;                                              \
        _Pragma("unroll")                                                       \
        for (int it = 0; it < 4; ++it)                                          \
            av[it] = *(const uint4*)(hb + aBase + (size_t)(it * 64) * INTR + k0_); \
        _Pragma("unroll")                                                       \
        for (int j = 0; j < 4; ++j) c2[j] = *(const int4*)(p2 + k0_ + j * 4);   \
        sc = s2[sBase + (KS)]; zz = z2[sBase + (KS)];                           \
    } while (0)

    DN_LOAD(0);

    for (int ks = 0; ks < INTR / BK; ++ks) {
        const float of = -zz * sc;
        const float scl = sc;
#pragma unroll
        for (int it = 0; it < 4; ++it) {
            int row = it * 64 + ar;
            *(uint4*)(&sA[row * BK + ((ac ^ (row & 7)) << 3)]) = av[it];
        }
        {
            uint4 lo, hi;
            lo.x = dq2(c2[0].x, c2[0].y, scl, of);
            lo.y = dq2(c2[0].z, c2[0].w, scl, of);
            lo.z = dq2(c2[1].x, c2[1].y, scl, of);
            lo.w = dq2(c2[1].z, c2[1].w, scl, of);
            hi.x = dq2(c2[2].x, c2[2].y, scl, of);
            hi.y = dq2(c2[2].z, c2[2].w, scl, of);
            hi.z = dq2(c2[3].x, c2[3].y, scl, of);
            hi.w = dq2(c2[3].z, c2[3].w, scl, of);
            *(uint4*)(&sB[br * BK + (( bc0      ^ r7) << 3)]) = lo;
            *(uint4*)(&sB[br * BK + (((bc0 + 1) ^ r7) << 3)]) = hi;
        }
        __syncthreads();

        if (ks + 1 < INTR / BK) DN_LOAD(ks + 1);

#pragma unroll
        for (int kk = 0; kk < 2; ++kk) {
            short8 af[4], bf[4];
#pragma unroll
            for (int m = 0; m < 4; ++m) {
                int row = wr * 64 + m * 16 + fr;
                af[m] = *(const short8*)(&sA[row * BK + ((((kk << 2) | fq) ^ (row & 7)) << 3)]);
            }
#pragma unroll
            for (int n = 0; n < 4; ++n) {
                int row = wc * 64 + n * 16 + fr;
                bf[n] = *(const short8*)(&sB[row * BK + ((((kk << 2) | fq) ^ (row & 7)) << 3)]);
            }
#pragma unroll
            for (int m = 0; m < 4; ++m)
#pragma unroll
                for (int n = 0; n < 4; ++n)
                    acc[m][n] = __builtin_amdgcn_mfma_f32_16x16x32_bf16(af[m], bf[n], acc[m][n], 0, 0, 0);
        }
        __syncthreads();
    }
#undef DN_LOAD

    // -- epilogue: stage fp32 tile through LDS in two 128-row passes --
    float* sO = (float*)smem;   // [128][128] f32 = 64 KB
#pragma unroll
    for (int half = 0; half < 2; ++half) {
        if (half) __syncthreads();
        if ((wr >> 1) == half) {
#pragma unroll
            for (int m = 0; m < 4; ++m)
#pragma unroll
                for (int n = 0; n < 4; ++n)
#pragma unroll
                    for (int r = 0; r < 4; ++r) {
                        int lr = (wr & 1) * 64 + m * 16 + fq * 4 + r;
                        int lc = wc * 64 + n * 16 + fr;
                        sO[lr * 128 + lc] = acc[m][n][r];
                    }
        }
        __syncthreads();
#pragma unroll
        for (int it = 0; it < 8; ++it) {
            int idx = it * 512 + tid;      // 16B units, 4096 total
            int row = idx >> 5;            // 512B per row
            int cu  = idx & 31;
            float4 v = ((const float4*)sO)[idx];
            *(float4*)(&out[(size_t)(row0 + half * 128 + row) * HID + col0 + (cu << 2)]) = v;
        }
    }
}

// ---- launcher --------------------------------------------------------------

extern "C" void kernel_launch(void* const* d_in, const int* in_sizes, int n_in,
                              void* d_out, int out_size, void* d_ws, size_t ws_size,
                              hipStream_t stream) {
    (void)in_sizes; (void)n_in; (void)out_size; (void)ws_size;

    const float* hs  = (const float*)d_in[0];
    const int*   w1q = (const int*)  d_in[1];
    const float* w1s = (const float*)d_in[2];
    const float* w1z = (const float*)d_in[3];
    const int*   w3q = (const int*)  d_in[4];
    const float* w3s = (const float*)d_in[5];
    const float* w3z = (const float*)d_in[6];
    const int*   w2q = (const int*)  d_in[7];
    const float* w2s = (const float*)d_in[8];
    const float* w2z = (const float*)d_in[9];
    float* out = (float*)d_out;

    u16* hsb  = (u16*)d_ws;                       // [TOK][HID]  bf16 (32 MB)
    u16* hmid = hsb + (size_t)TOK * HID;          // [TOK][INTR] bf16 (117 MB)

    cvt_hs_kernel<<<(TOK * HID / 8) / 256, 256, 0, stream>>>(hs, hsb);

    dim3 g2(TOK / BM, INTR / BN);
    gateup_kernel<<<g2, 512, 0, stream>>>(hsb, w1q, w1s, w1z, w3q, w3s, w3z, hmid);

    dim3 g3(TOK / BM, HID / BN);
    down_kernel<<<g3, 512, 0, stream>>>(hmid, w2q, w2s, w2z, out);
}

// Round 3
// 3445.560 us; speedup vs baseline: 1.2690x; 1.2297x over previous
//
#include <hip/hip_runtime.h>
#include <hip/hip_bf16.h>
#include <stdint.h>

#define HID  4096
#define INTR 14336
#define GS   64
#define TOK  4096
#define GRP1 (HID / GS)    // 64 groups along K for w1/w3
#define GRP2 (INTR / GS)   // 224 groups along K for w2

#define BM 256
#define BN 128
#define BK 64

typedef __attribute__((ext_vector_type(8))) short short8;  // 8 bf16 (4 VGPR)
typedef __attribute__((ext_vector_type(4))) float f32x4;   // MFMA acc
typedef unsigned short u16;
typedef unsigned int   u32;

// ---- helpers -------------------------------------------------------------

__device__ __forceinline__ u16 f2b(float x) {
    return __builtin_bit_cast(u16, __float2bfloat16(x));
}

__device__ __forceinline__ u32 pk2(float a, float b) {
    return (u32)f2b(a) | ((u32)f2b(b) << 16);
}

// dequant two int codes -> packed bf16 pair;  w = c*s + off  (off = -zero*s)
__device__ __forceinline__ u32 dq2(int ca, int cb, float s, float off) {
    return pk2(fmaf((float)ca, s, off), fmaf((float)cb, s, off));
}

// dequant 8 codes packed in one u32 -> 4 packed bf16 pairs
__device__ __forceinline__ uint4 dqw(u32 w, float s, float off) {
    uint4 v;
    v.x = dq2((int)( w        & 15), (int)((w >>  4) & 15), s, off);
    v.y = dq2((int)((w >>  8) & 15), (int)((w >> 12) & 15), s, off);
    v.z = dq2((int)((w >> 16) & 15), (int)((w >> 20) & 15), s, off);
    v.w = dq2((int)((w >> 24) & 15), (int)( w >> 28       ), s, off);
    return v;
}

// ---- repack: int32 codes -> 8x 4-bit nibbles per u32 ----------------------

__global__ void pack_kernel(const int* __restrict__ q, u32* __restrict__ p) {
    int i = blockIdx.x * blockDim.x + threadIdx.x;   // one output word
    const int4* s = (const int4*)q + (size_t)i * 2;
    int4 a = s[0], b = s[1];
    u32 w = (u32)(a.x & 15)        | ((u32)(a.y & 15) << 4)
          | ((u32)(a.z & 15) << 8) | ((u32)(a.w & 15) << 12)
          | ((u32)(b.x & 15) << 16)| ((u32)(b.y & 15) << 20)
          | ((u32)(b.z & 15) << 24)| ((u32)(b.w & 15) << 28);
    p[i] = w;
}

// ---- kernel 1: hs fp32 -> bf16 -------------------------------------------

__global__ void cvt_hs_kernel(const float* __restrict__ x, u16* __restrict__ y) {
    int i = blockIdx.x * blockDim.x + threadIdx.x;   // 8 elems per thread
    const float4* xp = (const float4*)x + (size_t)i * 2;
    float4 a = xp[0], b = xp[1];
    uint4 o;
    o.x = pk2(a.x, a.y); o.y = pk2(a.z, a.w);
    o.z = pk2(b.x, b.y); o.w = pk2(b.z, b.w);
    ((uint4*)y)[i] = o;
}

// ---- kernel 2: fused gate+up dual GEMM + SiLU*mul -------------------------

template<bool PK>
__global__ __launch_bounds__(512) void gateup_kernel(
    const u16* __restrict__ hsb,
    const int* __restrict__ w1q, const u32* __restrict__ w1p,
    const float* __restrict__ s1, const float* __restrict__ z1,
    const int* __restrict__ w3q, const u32* __restrict__ w3p,
    const float* __restrict__ s3, const float* __restrict__ z3,
    u16* __restrict__ hout)
{
    __shared__ __align__(16) char smem[64 * 1024];
    u16* sA  = (u16*)smem;             // 32 KB [256][64] swizzled
    u16* sB1 = (u16*)(smem + 32768);   // 16 KB [128][64]
    u16* sB3 = (u16*)(smem + 49152);   // 16 KB

    const int tid  = threadIdx.x;
    const int row0 = blockIdx.x * BM;
    const int col0 = blockIdx.y * BN;

    const int l   = tid & 63;
    const int wid = tid >> 6;      // 0..7
    const int wr  = wid >> 1;      // 0..3 (M)
    const int wc  = wid & 1;       // 0..1 (N)
    const int fq  = l >> 4;        // 0..3
    const int fr  = l & 15;        // 0..15

    f32x4 accg[4][4];
    f32x4 accu[4][4];
#pragma unroll
    for (int m = 0; m < 4; ++m)
#pragma unroll
        for (int n = 0; n < 4; ++n) {
            accg[m][n] = (f32x4){0.f, 0.f, 0.f, 0.f};
            accu[m][n] = (f32x4){0.f, 0.f, 0.f, 0.f};
        }

    const int ar  = tid >> 3;           // A: row within 64-row chunk
    const int ac  = tid & 7;            // A: 16B chunk index 0..7
    const int br  = tid >> 2;           // B: row 0..127
    const int bc0 = (tid & 3) << 1;     // B: chunk base 0,2,4,6
    const int r7  = br & 7;

    const size_t aBase = (size_t)(row0 + ar) * HID + (ac << 3);
    const int* q1 = w1q + (size_t)(col0 + br) * HID + ((tid & 3) << 4);
    const int* q3 = w3q + (size_t)(col0 + br) * HID + ((tid & 3) << 4);
    const u32* pp1 = w1p + (size_t)(col0 + br) * (HID / 8) + ((tid & 3) << 1);
    const u32* pp3 = w3p + (size_t)(col0 + br) * (HID / 8) + ((tid & 3) << 1);
    const size_t sBase = (size_t)(col0 + br) * GRP1;

    uint4 av[4];
    int4  c1[4], c3[4];
    uint2 g1, g3;
    float sc1, zz1, sc3, zz3;

    auto LOAD = [&](int KS) {
        const int k0 = KS * BK;
#pragma unroll
        for (int it = 0; it < 4; ++it)
            av[it] = *(const uint4*)(hsb + aBase + (size_t)(it * 64) * HID + k0);
        if constexpr (PK) {
            g1 = *(const uint2*)(pp1 + KS * 8);
            g3 = *(const uint2*)(pp3 + KS * 8);
        } else {
#pragma unroll
            for (int j = 0; j < 4; ++j) c1[j] = *(const int4*)(q1 + k0 + j * 4);
#pragma unroll
            for (int j = 0; j < 4; ++j) c3[j] = *(const int4*)(q3 + k0 + j * 4);
        }
        sc1 = s1[sBase + KS]; zz1 = z1[sBase + KS];
        sc3 = s3[sBase + KS]; zz3 = z3[sBase + KS];
    };

    LOAD(0);

    for (int ks = 0; ks < HID / BK; ++ks) {
        const float of1 = -zz1 * sc1;
        const float of3 = -zz3 * sc3;
        const float l1 = sc1, l3 = sc3;
#pragma unroll
        for (int it = 0; it < 4; ++it) {
            int row = it * 64 + ar;
            *(uint4*)(&sA[row * BK + ((ac ^ (row & 7)) << 3)]) = av[it];
        }
        {
            uint4 lo, hi;
            if constexpr (PK) {
                lo = dqw(g1.x, l1, of1);
                hi = dqw(g1.y, l1, of1);
            } else {
                lo.x = dq2(c1[0].x, c1[0].y, l1, of1);
                lo.y = dq2(c1[0].z, c1[0].w, l1, of1);
                lo.z = dq2(c1[1].x, c1[1].y, l1, of1);
                lo.w = dq2(c1[1].z, c1[1].w, l1, of1);
                hi.x = dq2(c1[2].x, c1[2].y, l1, of1);
                hi.y = dq2(c1[2].z, c1[2].w, l1, of1);
                hi.z = dq2(c1[3].x, c1[3].y, l1, of1);
                hi.w = dq2(c1[3].z, c1[3].w, l1, of1);
            }
            *(uint4*)(&sB1[br * BK + (( bc0      ^ r7) << 3)]) = lo;
            *(uint4*)(&sB1[br * BK + (((bc0 + 1) ^ r7) << 3)]) = hi;
            if constexpr (PK) {
                lo = dqw(g3.x, l3, of3);
                hi = dqw(g3.y, l3, of3);
            } else {
                lo.x = dq2(c3[0].x, c3[0].y, l3, of3);
                lo.y = dq2(c3[0].z, c3[0].w, l3, of3);
                lo.z = dq2(c3[1].x, c3[1].y, l3, of3);
                lo.w = dq2(c3[1].z, c3[1].w, l3, of3);
                hi.x = dq2(c3[2].x, c3[2].y, l3, of3);
                hi.y = dq2(c3[2].z, c3[2].w, l3, of3);
                hi.z = dq2(c3[3].x, c3[3].y, l3, of3);
                hi.w = dq2(c3[3].z, c3[3].w, l3, of3);
            }
            *(uint4*)(&sB3[br * BK + (( bc0      ^ r7) << 3)]) = lo;
            *(uint4*)(&sB3[br * BK + (((bc0 + 1) ^ r7) << 3)]) = hi;
        }

        // issue next tile's loads before the barrier; they land under MFMA
        if (ks + 1 < HID / BK) LOAD(ks + 1);

        __syncthreads();

#pragma unroll
        for (int kk = 0; kk < 2; ++kk) {
            short8 af[4], b1f[4], b3f[4];
#pragma unroll
            for (int m = 0; m < 4; ++m) {
                int row = wr * 64 + m * 16 + fr;
                af[m] = *(const short8*)(&sA[row * BK + ((((kk << 2) | fq) ^ (row & 7)) << 3)]);
            }
#pragma unroll
            for (int n = 0; n < 4; ++n) {
                int row = wc * 64 + n * 16 + fr;
                int ch  = (((kk << 2) | fq) ^ (row & 7)) << 3;
                b1f[n] = *(const short8*)(&sB1[row * BK + ch]);
                b3f[n] = *(const short8*)(&sB3[row * BK + ch]);
            }
#pragma unroll
            for (int m = 0; m < 4; ++m)
#pragma unroll
                for (int n = 0; n < 4; ++n) {
                    accg[m][n] = __builtin_amdgcn_mfma_f32_16x16x32_bf16(af[m], b1f[n], accg[m][n], 0, 0, 0);
                    accu[m][n] = __builtin_amdgcn_mfma_f32_16x16x32_bf16(af[m], b3f[n], accu[m][n], 0, 0, 0);
                }
        }
        __syncthreads();
    }

    // -- epilogue: silu(g)*u -> swizzled LDS stage -> coalesced stores --
    u16* sO = (u16*)smem;    // [256][128] bf16 = 64 KB
#pragma unroll
    for (int m = 0; m < 4; ++m)
#pragma unroll
        for (int n = 0; n < 4; ++n)
#pragma unroll
            for (int r = 0; r < 4; ++r) {
                int lr = wr * 64 + m * 16 + fq * 4 + r;
                int lc = wc * 64 + n * 16 + fr;
                float g = accg[m][n][r];
                float u = accu[m][n][r];
                float hv = (g / (1.0f + __expf(-g))) * u;
                int cs = ((((lc >> 3) ^ (lr & 7)) << 3) | (lc & 7));
                sO[lr * 128 + cs] = f2b(hv);
            }
    __syncthreads();
#pragma unroll
    for (int it = 0; it < 8; ++it) {
        int idx = it * 512 + tid;          // 16B units, 4096 total
        int row = idx >> 4;
        int cu  = idx & 15;
        uint4 v = ((const uint4*)sO)[row * 16 + (cu ^ (row & 7))];
        *(uint4*)(&hout[(size_t)(row0 + row) * INTR + col0 + (cu << 3)]) = v;
    }
}

// ---- kernel 3: down proj --------------------------------------------------

template<bool PK>
__global__ __launch_bounds__(512) void down_kernel(
    const u16* __restrict__ hb,
    const int* __restrict__ w2q, const u32* __restrict__ w2p,
    const float* __restrict__ s2, const float* __restrict__ z2,
    float* __restrict__ out)
{
    __shared__ __align__(16) char smem[64 * 1024];
    u16* sA = (u16*)smem;              // 32 KB
    u16* sB = (u16*)(smem + 32768);    // 16 KB

    const int tid  = threadIdx.x;
    const int row0 = blockIdx.x * BM;
    const int col0 = blockIdx.y * BN;

    const int l   = tid & 63;
    const int wid = tid >> 6;
    const int wr  = wid >> 1;
    const int wc  = wid & 1;
    const int fq  = l >> 4;
    const int fr  = l & 15;

    f32x4 acc[4][4];
#pragma unroll
    for (int m = 0; m < 4; ++m)
#pragma unroll
        for (int n = 0; n < 4; ++n)
            acc[m][n] = (f32x4){0.f, 0.f, 0.f, 0.f};

    const int ar  = tid >> 3;
    const int ac  = tid & 7;
    const int br  = tid >> 2;
    const int bc0 = (tid & 3) << 1;
    const int r7  = br & 7;

    const size_t aBase = (size_t)(row0 + ar) * INTR + (ac << 3);
    const int* q2 = w2q + (size_t)(col0 + br) * INTR + ((tid & 3) << 4);
    const u32* pp2 = w2p + (size_t)(col0 + br) * (INTR / 8) + ((tid & 3) << 1);
    const size_t sBase = (size_t)(col0 + br) * GRP2;

    uint4 av[4];
    int4  c2[4];
    uint2 g2;
    float sc, zz;

    auto LOAD = [&](int KS) {
        const int k0 = KS * BK;
#pragma unroll
        for (int it = 0; it < 4; ++it)
            av[it] = *(const uint4*)(hb + aBase + (size_t)(it * 64) * INTR + k0);
        if constexpr (PK) {
            g2 = *(const uint2*)(pp2 + KS * 8);
        } else {
#pragma unroll
            for (int j = 0; j < 4; ++j) c2[j] = *(const int4*)(q2 + k0 + j * 4);
        }
        sc = s2[sBase + KS]; zz = z2[sBase + KS];
    };

    LOAD(0);

    for (int ks = 0; ks < INTR / BK; ++ks) {
        const float of = -zz * sc;
        const float scl = sc;
#pragma unroll
        for (int it = 0; it < 4; ++it) {
            int row = it * 64 + ar;
            *(uint4*)(&sA[row * BK + ((ac ^ (row & 7)) << 3)]) = av[it];
        }
        {
            uint4 lo, hi;
            if constexpr (PK) {
                lo = dqw(g2.x, scl, of);
                hi = dqw(g2.y, scl, of);
            } else {
                lo.x = dq2(c2[0].x, c2[0].y, scl, of);
                lo.y = dq2(c2[0].z, c2[0].w, scl, of);
                lo.z = dq2(c2[1].x, c2[1].y, scl, of);
                lo.w = dq2(c2[1].z, c2[1].w, scl, of);
                hi.x = dq2(c2[2].x, c2[2].y, scl, of);
                hi.y = dq2(c2[2].z, c2[2].w, scl, of);
                hi.z = dq2(c2[3].x, c2[3].y, scl, of);
                hi.w = dq2(c2[3].z, c2[3].w, scl, of);
            }
            *(uint4*)(&sB[br * BK + (( bc0      ^ r7) << 3)]) = lo;
            *(uint4*)(&sB[br * BK + (((bc0 + 1) ^ r7) << 3)]) = hi;
        }

        if (ks + 1 < INTR / BK) LOAD(ks + 1);

        __syncthreads();

#pragma unroll
        for (int kk = 0; kk < 2; ++kk) {
            short8 af[4], bf[4];
#pragma unroll
            for (int m = 0; m < 4; ++m) {
                int row = wr * 64 + m * 16 + fr;
                af[m] = *(const short8*)(&sA[row * BK + ((((kk << 2) | fq) ^ (row & 7)) << 3)]);
            }
#pragma unroll
            for (int n = 0; n < 4; ++n) {
                int row = wc * 64 + n * 16 + fr;
                bf[n] = *(const short8*)(&sB[row * BK + ((((kk << 2) | fq) ^ (row & 7)) << 3)]);
            }
#pragma unroll
            for (int m = 0; m < 4; ++m)
#pragma unroll
                for (int n = 0; n < 4; ++n)
                    acc[m][n] = __builtin_amdgcn_mfma_f32_16x16x32_bf16(af[m], bf[n], acc[m][n], 0, 0, 0);
        }
        __syncthreads();
    }

    // -- epilogue: swizzled fp32 LDS stage, two 128-row passes --
    float* sO = (float*)smem;   // [128][128] f32 = 64 KB
#pragma unroll
    for (int half = 0; half < 2; ++half) {
        if (half) __syncthreads();
        if ((wr >> 1) == half) {
#pragma unroll
            for (int m = 0; m < 4; ++m)
#pragma unroll
                for (int n = 0; n < 4; ++n)
#pragma unroll
                    for (int r = 0; r < 4; ++r) {
                        int lr = (wr & 1) * 64 + m * 16 + fq * 4 + r;
                        int lc = wc * 64 + n * 16 + fr;
                        int cs = ((((lc >> 2) ^ (lr & 7)) << 2) | (lc & 3));
                        sO[lr * 128 + cs] = acc[m][n][r];
                    }
        }
        __syncthreads();
#pragma unroll
        for (int it = 0; it < 8; ++it) {
            int idx = it * 512 + tid;      // 16B units, 4096 total
            int row = idx >> 5;
            int ch  = idx & 31;
            float4 v = ((const float4*)sO)[row * 32 + (ch ^ (row & 7))];
            *(float4*)(&out[(size_t)(row0 + half * 128 + row) * HID + col0 + (ch << 2)]) = v;
        }
    }
}

// ---- launcher --------------------------------------------------------------

extern "C" void kernel_launch(void* const* d_in, const int* in_sizes, int n_in,
                              void* d_out, int out_size, void* d_ws, size_t ws_size,
                              hipStream_t stream) {
    (void)in_sizes; (void)n_in; (void)out_size;

    const float* hs  = (const float*)d_in[0];
    const int*   w1q = (const int*)  d_in[1];
    const float* w1s = (const float*)d_in[2];
    const float* w1z = (const float*)d_in[3];
    const int*   w3q = (const int*)  d_in[4];
    const float* w3s = (const float*)d_in[5];
    const float* w3z = (const float*)d_in[6];
    const int*   w2q = (const int*)  d_in[7];
    const float* w2s = (const float*)d_in[8];
    const float* w2z = (const float*)d_in[9];
    float* out = (float*)d_out;

    const size_t NWRD = (size_t)INTR * HID / 8;   // packed words per weight
    u16* hsb  = (u16*)d_ws;                       // 32 MB
    u16* hmid = hsb + (size_t)TOK * HID;          // 117 MB
    u32* w1p  = (u32*)(hmid + (size_t)TOK * INTR);
    u32* w3p  = w1p + NWRD;
    u32* w2p  = w3p + NWRD;

    const size_t need = (size_t)TOK * HID * 2 + (size_t)TOK * INTR * 2 + 3 * NWRD * 4;
    const bool pk = ws_size >= need;

    cvt_hs_kernel<<<(TOK * HID / 8) / 256, 256, 0, stream>>>(hs, hsb);

    dim3 g2(TOK / BM, INTR / BN);
    dim3 g3(TOK / BM, HID / BN);

    if (pk) {
        const int pgrid = (int)(NWRD / 256);      // 28672
        pack_kernel<<<pgrid, 256, 0, stream>>>(w1q, w1p);
        pack_kernel<<<pgrid, 256, 0, stream>>>(w3q, w3p);
        pack_kernel<<<pgrid, 256, 0, stream>>>(w2q, w2p);
        gateup_kernel<true><<<g2, 512, 0, stream>>>(hsb, w1q, w1p, w1s, w1z,
                                                    w3q, w3p, w3s, w3z, hmid);
        down_kernel<true><<<g3, 512, 0, stream>>>(hmid, w2q, w2p, w2s, w2z, out);
    } else {
        gateup_kernel<false><<<g2, 512, 0, stream>>>(hsb, w1q, nullptr, w1s, w1z,
                                                     w3q, nullptr, w3s, w3z, hmid);
        down_kernel<false><<<g3, 512, 0, stream>>>(hmid, w2q, nullptr, w2s, w2z, out);
    }
}

// Round 4
// 2120.033 us; speedup vs baseline: 2.0625x; 1.6252x over previous
//
#include <hip/hip_runtime.h>
#include <hip/hip_bf16.h>
#include <stdint.h>

#define HID  4096
#define INTR 14336
#define GS   64
#define TOK  4096
#define GRP1 (HID / GS)    // 64 groups along K for w1/w3
#define GRP2 (INTR / GS)   // 224 groups along K for w2

#define BM 256
#define BN 128
#define BK 64

typedef __attribute__((ext_vector_type(8))) short short8;  // 8 bf16 (4 VGPR)
typedef __attribute__((ext_vector_type(4))) float f32x4;   // MFMA acc
typedef unsigned short u16;
typedef unsigned int   u32;

// ---- helpers -------------------------------------------------------------

__device__ __forceinline__ u16 f2b(float x) {
    return __builtin_bit_cast(u16, __float2bfloat16(x));
}

__device__ __forceinline__ u32 pk2(float a, float b) {
    return (u32)f2b(a) | ((u32)f2b(b) << 16);
}

// dequant two int codes -> packed bf16 pair;  w = c*s + off  (off = -zero*s)
__device__ __forceinline__ u32 dq2(int ca, int cb, float s, float off) {
    return pk2(fmaf((float)ca, s, off), fmaf((float)cb, s, off));
}

// dequant 8 codes packed in one u32 -> 4 packed bf16 pairs
__device__ __forceinline__ uint4 dqw(u32 w, float s, float off) {
    uint4 v;
    v.x = dq2((int)( w        & 15), (int)((w >>  4) & 15), s, off);
    v.y = dq2((int)((w >>  8) & 15), (int)((w >> 12) & 15), s, off);
    v.z = dq2((int)((w >> 16) & 15), (int)((w >> 20) & 15), s, off);
    v.w = dq2((int)((w >> 24) & 15), (int)( w >> 28       ), s, off);
    return v;
}

// ---- repack: int32 codes -> 8x 4-bit nibbles per u32 ----------------------

__global__ void pack_kernel(const int* __restrict__ q, u32* __restrict__ p) {
    int i = blockIdx.x * blockDim.x + threadIdx.x;   // one output word
    const int4* s = (const int4*)q + (size_t)i * 2;
    int4 a = s[0], b = s[1];
    u32 w = (u32)(a.x & 15)        | ((u32)(a.y & 15) << 4)
          | ((u32)(a.z & 15) << 8) | ((u32)(a.w & 15) << 12)
          | ((u32)(b.x & 15) << 16)| ((u32)(b.y & 15) << 20)
          | ((u32)(b.z & 15) << 24)| ((u32)(b.w & 15) << 28);
    p[i] = w;
}

// ---- kernel 1: hs fp32 -> bf16 -------------------------------------------

__global__ void cvt_hs_kernel(const float* __restrict__ x, u16* __restrict__ y) {
    int i = blockIdx.x * blockDim.x + threadIdx.x;   // 8 elems per thread
    const float4* xp = (const float4*)x + (size_t)i * 2;
    float4 a = xp[0], b = xp[1];
    uint4 o;
    o.x = pk2(a.x, a.y); o.y = pk2(a.z, a.w);
    o.z = pk2(b.x, b.y); o.w = pk2(b.z, b.w);
    ((uint4*)y)[i] = o;
}

// ---- kernel 2: fused gate+up dual GEMM + SiLU*mul -------------------------
// Double-buffered LDS, ONE barrier per K-step. Step k: issue loads(k+1),
// MFMA on buf[k&1] (load latency hides under it), dequant+write buf[(k+1)&1],
// barrier. The vmcnt(0) drain at the barrier lands where data is needed.

template<bool PK>
__global__ __launch_bounds__(512) void gateup_kernel(
    const u16* __restrict__ hsb,
    const int* __restrict__ w1q, const u32* __restrict__ w1p,
    const float* __restrict__ s1, const float* __restrict__ z1,
    const int* __restrict__ w3q, const u32* __restrict__ w3p,
    const float* __restrict__ s3, const float* __restrict__ z3,
    u16* __restrict__ hout)
{
    __shared__ __align__(16) char smem[131072];   // 2 x (A 32K | B1 16K | B3 16K)

    const int tid  = threadIdx.x;
    const int row0 = blockIdx.x * BM;
    const int col0 = blockIdx.y * BN;

    const int l   = tid & 63;
    const int wid = tid >> 6;      // 0..7
    const int wr  = wid >> 1;      // 0..3 (M)
    const int wc  = wid & 1;       // 0..1 (N)
    const int fq  = l >> 4;        // 0..3
    const int fr  = l & 15;        // 0..15

    f32x4 accg[4][4];
    f32x4 accu[4][4];
#pragma unroll
    for (int m = 0; m < 4; ++m)
#pragma unroll
        for (int n = 0; n < 4; ++n) {
            accg[m][n] = (f32x4){0.f, 0.f, 0.f, 0.f};
            accu[m][n] = (f32x4){0.f, 0.f, 0.f, 0.f};
        }

    const int ar  = tid >> 3;           // A: row within 64-row chunk
    const int ac  = tid & 7;            // A: 16B chunk index 0..7
    const int br  = tid >> 2;           // B: row 0..127
    const int bc0 = (tid & 3) << 1;     // B: chunk base 0,2,4,6
    const int r7  = br & 7;

    const size_t aBase = (size_t)(row0 + ar) * HID + (ac << 3);
    const int* q1 = w1q + (size_t)(col0 + br) * HID + ((tid & 3) << 4);
    const int* q3 = w3q + (size_t)(col0 + br) * HID + ((tid & 3) << 4);
    const u32* pp1 = w1p + (size_t)(col0 + br) * (HID / 8) + ((tid & 3) << 1);
    const u32* pp3 = w3p + (size_t)(col0 + br) * (HID / 8) + ((tid & 3) << 1);
    const size_t sBase = (size_t)(col0 + br) * GRP1;

    uint4 av[4];
    int4  c1[4], c3[4];
    uint2 g1, g3;
    float sc1, zz1, sc3, zz3;

    auto LOAD = [&](int KS) {
        const int k0 = KS * BK;
#pragma unroll
        for (int it = 0; it < 4; ++it)
            av[it] = *(const uint4*)(hsb + aBase + (size_t)(it * 64) * HID + k0);
        if constexpr (PK) {
            g1 = *(const uint2*)(pp1 + KS * 8);
            g3 = *(const uint2*)(pp3 + KS * 8);
        } else {
#pragma unroll
            for (int j = 0; j < 4; ++j) c1[j] = *(const int4*)(q1 + k0 + j * 4);
#pragma unroll
            for (int j = 0; j < 4; ++j) c3[j] = *(const int4*)(q3 + k0 + j * 4);
        }
        sc1 = s1[sBase + KS]; zz1 = z1[sBase + KS];
        sc3 = s3[sBase + KS]; zz3 = z3[sBase + KS];
    };

    // dequant regs -> LDS buffer bsel (XOR chunk swizzle: chunk ^= row&7)
    auto DEQW = [&](int bsel) {
        u16* dA  = (u16*)(smem + bsel * 65536);
        u16* dB1 = (u16*)(smem + bsel * 65536 + 32768);
        u16* dB3 = (u16*)(smem + bsel * 65536 + 49152);
#pragma unroll
        for (int it = 0; it < 4; ++it) {
            int row = it * 64 + ar;
            *(uint4*)(&dA[row * BK + ((ac ^ (row & 7)) << 3)]) = av[it];
        }
        const float of1 = -zz1 * sc1;
        const float of3 = -zz3 * sc3;
        uint4 lo, hi;
        if constexpr (PK) {
            lo = dqw(g1.x, sc1, of1);
            hi = dqw(g1.y, sc1, of1);
        } else {
            lo.x = dq2(c1[0].x, c1[0].y, sc1, of1);
            lo.y = dq2(c1[0].z, c1[0].w, sc1, of1);
            lo.z = dq2(c1[1].x, c1[1].y, sc1, of1);
            lo.w = dq2(c1[1].z, c1[1].w, sc1, of1);
            hi.x = dq2(c1[2].x, c1[2].y, sc1, of1);
            hi.y = dq2(c1[2].z, c1[2].w, sc1, of1);
            hi.z = dq2(c1[3].x, c1[3].y, sc1, of1);
            hi.w = dq2(c1[3].z, c1[3].w, sc1, of1);
        }
        *(uint4*)(&dB1[br * BK + (( bc0      ^ r7) << 3)]) = lo;
        *(uint4*)(&dB1[br * BK + (((bc0 + 1) ^ r7) << 3)]) = hi;
        if constexpr (PK) {
            lo = dqw(g3.x, sc3, of3);
            hi = dqw(g3.y, sc3, of3);
        } else {
            lo.x = dq2(c3[0].x, c3[0].y, sc3, of3);
            lo.y = dq2(c3[0].z, c3[0].w, sc3, of3);
            lo.z = dq2(c3[1].x, c3[1].y, sc3, of3);
            lo.w = dq2(c3[1].z, c3[1].w, sc3, of3);
            hi.x = dq2(c3[2].x, c3[2].y, sc3, of3);
            hi.y = dq2(c3[2].z, c3[2].w, sc3, of3);
            hi.z = dq2(c3[3].x, c3[3].y, sc3, of3);
            hi.w = dq2(c3[3].z, c3[3].w, sc3, of3);
        }
        *(uint4*)(&dB3[br * BK + (( bc0      ^ r7) << 3)]) = lo;
        *(uint4*)(&dB3[br * BK + (((bc0 + 1) ^ r7) << 3)]) = hi;
    };

    const int NK = HID / BK;   // 64

    // prologue: stage tile 0 into buf0
    LOAD(0);
    DEQW(0);
    __syncthreads();

    for (int ks = 0; ks < NK; ++ks) {
        // 1. issue loads for tile ks+1 (clamped re-load at the tail)
        LOAD(ks + 1 < NK ? ks + 1 : NK - 1);

        // 2. MFMA on buf[ks&1] — load latency hides under this phase
        const int cur = ks & 1;
        const u16* bA  = (const u16*)(smem + cur * 65536);
        const u16* bB1 = (const u16*)(smem + cur * 65536 + 32768);
        const u16* bB3 = (const u16*)(smem + cur * 65536 + 49152);
#pragma unroll
        for (int kk = 0; kk < 2; ++kk) {
            short8 af[4], b1f[4], b3f[4];
#pragma unroll
            for (int m = 0; m < 4; ++m) {
                int row = wr * 64 + m * 16 + fr;
                af[m] = *(const short8*)(&bA[row * BK + ((((kk << 2) | fq) ^ (row & 7)) << 3)]);
            }
#pragma unroll
            for (int n = 0; n < 4; ++n) {
                int row = wc * 64 + n * 16 + fr;
                int ch  = (((kk << 2) | fq) ^ (row & 7)) << 3;
                b1f[n] = *(const short8*)(&bB1[row * BK + ch]);
                b3f[n] = *(const short8*)(&bB3[row * BK + ch]);
            }
#pragma unroll
            for (int m = 0; m < 4; ++m)
#pragma unroll
                for (int n = 0; n < 4; ++n) {
                    accg[m][n] = __builtin_amdgcn_mfma_f32_16x16x32_bf16(af[m], b1f[n], accg[m][n], 0, 0, 0);
                    accu[m][n] = __builtin_amdgcn_mfma_f32_16x16x32_bf16(af[m], b3f[n], accu[m][n], 0, 0, 0);
                }
        }

        // 3. dequant tile ks+1 -> other buffer
        DEQW(cur ^ 1);

        // 4. single barrier per step
        __syncthreads();
    }

    // -- epilogue: silu(g)*u -> swizzled LDS stage -> coalesced stores --
    u16* sO = (u16*)smem;    // [256][128] bf16 = 64 KB
#pragma unroll
    for (int m = 0; m < 4; ++m)
#pragma unroll
        for (int n = 0; n < 4; ++n)
#pragma unroll
            for (int r = 0; r < 4; ++r) {
                int lr = wr * 64 + m * 16 + fq * 4 + r;
                int lc = wc * 64 + n * 16 + fr;
                float g = accg[m][n][r];
                float u = accu[m][n][r];
                float hv = (g / (1.0f + __expf(-g))) * u;
                int cs = ((((lc >> 3) ^ (lr & 7)) << 3) | (lc & 7));
                sO[lr * 128 + cs] = f2b(hv);
            }
    __syncthreads();
#pragma unroll
    for (int it = 0; it < 8; ++it) {
        int idx = it * 512 + tid;          // 16B units, 4096 total
        int row = idx >> 4;
        int cu  = idx & 15;
        uint4 v = ((const uint4*)sO)[row * 16 + (cu ^ (row & 7))];
        *(uint4*)(&hout[(size_t)(row0 + row) * INTR + col0 + (cu << 3)]) = v;
    }
}

// ---- kernel 3: down proj --------------------------------------------------

template<bool PK>
__global__ __launch_bounds__(512) void down_kernel(
    const u16* __restrict__ hb,
    const int* __restrict__ w2q, const u32* __restrict__ w2p,
    const float* __restrict__ s2, const float* __restrict__ z2,
    float* __restrict__ out)
{
    __shared__ __align__(16) char smem[98304];   // 2 x (A 32K | B 16K)

    const int tid  = threadIdx.x;
    const int row0 = blockIdx.x * BM;
    const int col0 = blockIdx.y * BN;

    const int l   = tid & 63;
    const int wid = tid >> 6;
    const int wr  = wid >> 1;
    const int wc  = wid & 1;
    const int fq  = l >> 4;
    const int fr  = l & 15;

    f32x4 acc[4][4];
#pragma unroll
    for (int m = 0; m < 4; ++m)
#pragma unroll
        for (int n = 0; n < 4; ++n)
            acc[m][n] = (f32x4){0.f, 0.f, 0.f, 0.f};

    const int ar  = tid >> 3;
    const int ac  = tid & 7;
    const int br  = tid >> 2;
    const int bc0 = (tid & 3) << 1;
    const int r7  = br & 7;

    const size_t aBase = (size_t)(row0 + ar) * INTR + (ac << 3);
    const int* q2 = w2q + (size_t)(col0 + br) * INTR + ((tid & 3) << 4);
    const u32* pp2 = w2p + (size_t)(col0 + br) * (INTR / 8) + ((tid & 3) << 1);
    const size_t sBase = (size_t)(col0 + br) * GRP2;

    uint4 av[4];
    int4  c2[4];
    uint2 g2;
    float sc, zz;

    auto LOAD = [&](int KS) {
        const int k0 = KS * BK;
#pragma unroll
        for (int it = 0; it < 4; ++it)
            av[it] = *(const uint4*)(hb + aBase + (size_t)(it * 64) * INTR + k0);
        if constexpr (PK) {
            g2 = *(const uint2*)(pp2 + KS * 8);
        } else {
#pragma unroll
            for (int j = 0; j < 4; ++j) c2[j] = *(const int4*)(q2 + k0 + j * 4);
        }
        sc = s2[sBase + KS]; zz = z2[sBase + KS];
    };

    auto DEQW = [&](int bsel) {
        u16* dA = (u16*)(smem + bsel * 49152);
        u16* dB = (u16*)(smem + bsel * 49152 + 32768);
#pragma unroll
        for (int it = 0; it < 4; ++it) {
            int row = it * 64 + ar;
            *(uint4*)(&dA[row * BK + ((ac ^ (row & 7)) << 3)]) = av[it];
        }
        const float of = -zz * sc;
        uint4 lo, hi;
        if constexpr (PK) {
            lo = dqw(g2.x, sc, of);
            hi = dqw(g2.y, sc, of);
        } else {
            lo.x = dq2(c2[0].x, c2[0].y, sc, of);
            lo.y = dq2(c2[0].z, c2[0].w, sc, of);
            lo.z = dq2(c2[1].x, c2[1].y, sc, of);
            lo.w = dq2(c2[1].z, c2[1].w, sc, of);
            hi.x = dq2(c2[2].x, c2[2].y, sc, of);
            hi.y = dq2(c2[2].z, c2[2].w, sc, of);
            hi.z = dq2(c2[3].x, c2[3].y, sc, of);
            hi.w = dq2(c2[3].z, c2[3].w, sc, of);
        }
        *(uint4*)(&dB[br * BK + (( bc0      ^ r7) << 3)]) = lo;
        *(uint4*)(&dB[br * BK + (((bc0 + 1) ^ r7) << 3)]) = hi;
    };

    const int NK = INTR / BK;   // 224

    LOAD(0);
    DEQW(0);
    __syncthreads();

    for (int ks = 0; ks < NK; ++ks) {
        LOAD(ks + 1 < NK ? ks + 1 : NK - 1);

        const int cur = ks & 1;
        const u16* bA = (const u16*)(smem + cur * 49152);
        const u16* bB = (const u16*)(smem + cur * 49152 + 32768);
#pragma unroll
        for (int kk = 0; kk < 2; ++kk) {
            short8 af[4], bf[4];
#pragma unroll
            for (int m = 0; m < 4; ++m) {
                int row = wr * 64 + m * 16 + fr;
                af[m] = *(const short8*)(&bA[row * BK + ((((kk << 2) | fq) ^ (row & 7)) << 3)]);
            }
#pragma unroll
            for (int n = 0; n < 4; ++n) {
                int row = wc * 64 + n * 16 + fr;
                bf[n] = *(const short8*)(&bB[row * BK + ((((kk << 2) | fq) ^ (row & 7)) << 3)]);
            }
#pragma unroll
            for (int m = 0; m < 4; ++m)
#pragma unroll
                for (int n = 0; n < 4; ++n)
                    acc[m][n] = __builtin_amdgcn_mfma_f32_16x16x32_bf16(af[m], bf[n], acc[m][n], 0, 0, 0);
        }

        DEQW(cur ^ 1);
        __syncthreads();
    }

    // -- epilogue: swizzled fp32 LDS stage, two 128-row passes --
    float* sO = (float*)smem;   // [128][128] f32 = 64 KB
#pragma unroll
    for (int half = 0; half < 2; ++half) {
        if (half) __syncthreads();
        if ((wr >> 1) == half) {
#pragma unroll
            for (int m = 0; m < 4; ++m)
#pragma unroll
                for (int n = 0; n < 4; ++n)
#pragma unroll
                    for (int r = 0; r < 4; ++r) {
                        int lr = (wr & 1) * 64 + m * 16 + fq * 4 + r;
                        int lc = wc * 64 + n * 16 + fr;
                        int cs = ((((lc >> 2) ^ (lr & 7)) << 2) | (lc & 3));
                        sO[lr * 128 + cs] = acc[m][n][r];
                    }
        }
        __syncthreads();
#pragma unroll
        for (int it = 0; it < 8; ++it) {
            int idx = it * 512 + tid;      // 16B units, 4096 total
            int row = idx >> 5;
            int ch  = idx & 31;
            float4 v = ((const float4*)sO)[row * 32 + (ch ^ (row & 7))];
            *(float4*)(&out[(size_t)(row0 + half * 128 + row) * HID + col0 + (ch << 2)]) = v;
        }
    }
}

// ---- launcher --------------------------------------------------------------

extern "C" void kernel_launch(void* const* d_in, const int* in_sizes, int n_in,
                              void* d_out, int out_size, void* d_ws, size_t ws_size,
                              hipStream_t stream) {
    (void)in_sizes; (void)n_in; (void)out_size;

    const float* hs  = (const float*)d_in[0];
    const int*   w1q = (const int*)  d_in[1];
    const float* w1s = (const float*)d_in[2];
    const float* w1z = (const float*)d_in[3];
    const int*   w3q = (const int*)  d_in[4];
    const float* w3s = (const float*)d_in[5];
    const float* w3z = (const float*)d_in[6];
    const int*   w2q = (const int*)  d_in[7];
    const float* w2s = (const float*)d_in[8];
    const float* w2z = (const float*)d_in[9];
    float* out = (float*)d_out;

    const size_t NWRD = (size_t)INTR * HID / 8;   // packed words per weight
    u16* hsb  = (u16*)d_ws;                       // 32 MB
    u16* hmid = hsb + (size_t)TOK * HID;          // 117 MB
    u32* w1p  = (u32*)(hmid + (size_t)TOK * INTR);
    u32* w3p  = w1p + NWRD;
    u32* w2p  = w3p + NWRD;

    const size_t need = (size_t)TOK * HID * 2 + (size_t)TOK * INTR * 2 + 3 * NWRD * 4;
    const bool pk = ws_size >= need;

    cvt_hs_kernel<<<(TOK * HID / 8) / 256, 256, 0, stream>>>(hs, hsb);

    dim3 g2(TOK / BM, INTR / BN);
    dim3 g3(TOK / BM, HID / BN);

    if (pk) {
        const int pgrid = (int)(NWRD / 256);      // 28672
        pack_kernel<<<pgrid, 256, 0, stream>>>(w1q, w1p);
        pack_kernel<<<pgrid, 256, 0, stream>>>(w3q, w3p);
        pack_kernel<<<pgrid, 256, 0, stream>>>(w2q, w2p);
        gateup_kernel<true><<<g2, 512, 0, stream>>>(hsb, w1q, w1p, w1s, w1z,
                                                    w3q, w3p, w3s, w3z, hmid);
        down_kernel<true><<<g3, 512, 0, stream>>>(hmid, w2q, w2p, w2s, w2z, out);
    } else {
        gateup_kernel<false><<<g2, 512, 0, stream>>>(hsb, w1q, nullptr, w1s, w1z,
                                                     w3q, nullptr, w3s, w3z, hmid);
        down_kernel<false><<<g3, 512, 0, stream>>>(hmid, w2q, nullptr, w2s, w2z, out);
    }
}

// Round 5
// 1665.248 us; speedup vs baseline: 2.6257x; 1.2731x over previous
//
#include <hip/hip_runtime.h>
#include <hip/hip_bf16.h>
#include <stdint.h>

#define HID  4096
#define INTR 14336
#define GS   64
#define TOK  4096
#define GRP1 (HID / GS)    // 64 groups along K for w1/w3
#define GRP2 (INTR / GS)   // 224 groups along K for w2

#define BM 256
#define BN 128
#define BK 64

typedef __attribute__((ext_vector_type(8))) short short8;  // 8 bf16 (4 VGPR)
typedef __attribute__((ext_vector_type(4))) float f32x4;   // MFMA acc
typedef unsigned short u16;
typedef unsigned int   u32;

// ---- helpers -------------------------------------------------------------

__device__ __forceinline__ u16 f2b(float x) {
    return __builtin_bit_cast(u16, __float2bfloat16(x));
}

__device__ __forceinline__ u32 pk2(float a, float b) {
    return (u32)f2b(a) | ((u32)f2b(b) << 16);
}

// dequant two int codes -> packed bf16 pair;  w = c*s + off  (off = -zero*s)
__device__ __forceinline__ u32 dq2(int ca, int cb, float s, float off) {
    return pk2(fmaf((float)ca, s, off), fmaf((float)cb, s, off));
}

// dequant 8 codes packed in one u32 -> 4 packed bf16 pairs
__device__ __forceinline__ uint4 dqw(u32 w, float s, float off) {
    uint4 v;
    v.x = dq2((int)( w        & 15), (int)((w >>  4) & 15), s, off);
    v.y = dq2((int)((w >>  8) & 15), (int)((w >> 12) & 15), s, off);
    v.z = dq2((int)((w >> 16) & 15), (int)((w >> 20) & 15), s, off);
    v.w = dq2((int)((w >> 24) & 15), (int)( w >> 28       ), s, off);
    return v;
}

// async global -> LDS, 16 bytes/lane, linear LDS dest (wave-uniform base + lane*16)
__device__ __forceinline__ void gload16(const void* g, void* l) {
    __builtin_amdgcn_global_load_lds(
        (const __attribute__((address_space(1))) void*)g,
        (__attribute__((address_space(3))) void*)l, 16, 0, 0);
}

// ---- repack: int32 codes -> 8x 4-bit nibbles per u32 ----------------------

__global__ void pack_kernel(const int* __restrict__ q, u32* __restrict__ p) {
    int i = blockIdx.x * blockDim.x + threadIdx.x;   // one output word
    const int4* s = (const int4*)q + (size_t)i * 2;
    int4 a = s[0], b = s[1];
    u32 w = (u32)(a.x & 15)        | ((u32)(a.y & 15) << 4)
          | ((u32)(a.z & 15) << 8) | ((u32)(a.w & 15) << 12)
          | ((u32)(b.x & 15) << 16)| ((u32)(b.y & 15) << 20)
          | ((u32)(b.z & 15) << 24)| ((u32)(b.w & 15) << 28);
    p[i] = w;
}

// ---- kernel 1: hs fp32 -> bf16, PRE-SWIZZLED ------------------------------
// Within each row's 64-elem K-group, 16B chunk c is stored at c ^ (t & 7).
// global_load_lds then copies rows linearly and the LDS ends up swizzled.

__global__ void cvt_hs_kernel(const float* __restrict__ x, u16* __restrict__ y) {
    int i = blockIdx.x * blockDim.x + threadIdx.x;   // one 8-elem chunk
    int t = i >> 9;            // HID/8 = 512 chunks per row
    int c = i & 511;
    const float4* xp = (const float4*)x + (size_t)i * 2;
    float4 a = xp[0], b = xp[1];
    uint4 o;
    o.x = pk2(a.x, a.y); o.y = pk2(a.z, a.w);
    o.z = pk2(b.x, b.y); o.w = pk2(b.z, b.w);
    int cs = (c & ~7) | ((c & 7) ^ (t & 7));
    ((uint4*)y)[(size_t)t * 512 + cs] = o;
}

// ---- kernel 2: fused gate+up dual GEMM + SiLU*mul -------------------------
// A staged via global_load_lds (linear dest, pre-swizzled source rows);
// B dequantized in regs -> swizzled ds_write. Double-buffered, 1 barrier.

template<bool PK>
__global__ __launch_bounds__(512) void gateup_kernel(
    const u16* __restrict__ hsb,
    const int* __restrict__ w1q, const u32* __restrict__ w1p,
    const float* __restrict__ s1, const float* __restrict__ z1,
    const int* __restrict__ w3q, const u32* __restrict__ w3p,
    const float* __restrict__ s3, const float* __restrict__ z3,
    u16* __restrict__ hout)
{
    __shared__ __align__(16) char smem[131072];   // 2 x (A 32K | B1 16K | B3 16K)

    const int tid  = threadIdx.x;
    const int row0 = blockIdx.x * BM;
    const int col0 = blockIdx.y * BN;

    const int l   = tid & 63;
    const int wid = tid >> 6;      // 0..7
    const int wr  = wid >> 1;      // 0..3 (M)
    const int wc  = wid & 1;       // 0..1 (N)
    const int fq  = l >> 4;        // 0..3
    const int fr  = l & 15;        // 0..15

    f32x4 accg[4][4];
    f32x4 accu[4][4];
#pragma unroll
    for (int m = 0; m < 4; ++m)
#pragma unroll
        for (int n = 0; n < 4; ++n) {
            accg[m][n] = (f32x4){0.f, 0.f, 0.f, 0.f};
            accu[m][n] = (f32x4){0.f, 0.f, 0.f, 0.f};
        }

    const int br  = tid >> 2;           // B: row 0..127
    const int bc0 = (tid & 3) << 1;     // B: chunk base 0,2,4,6
    const int r7  = br & 7;

    const u32* pp1 = w1p + (size_t)(col0 + br) * (HID / 8) + ((tid & 3) << 1);
    const u32* pp3 = w3p + (size_t)(col0 + br) * (HID / 8) + ((tid & 3) << 1);
    const int* q1 = w1q + (size_t)(col0 + br) * HID + ((tid & 3) << 4);
    const int* q3 = w3q + (size_t)(col0 + br) * HID + ((tid & 3) << 4);
    const size_t sBase = (size_t)(col0 + br) * GRP1;

    // A staging source: lane covers row (blk*8 + l>>3), chunk (l&7)
    const u16* aSrc = hsb + (size_t)(row0 + (l >> 3)) * HID + ((l & 7) << 3);

    int4  c1[4], c3[4];
    uint2 g1, g3;
    float sc1, zz1, sc3, zz3;

    // load B codes + scales into regs (issued BEFORE the A DMAs so using
    // them later only needs vmcnt(4), not a full drain)
    auto LOADB = [&](int KS) {
        if constexpr (PK) {
            g1 = *(const uint2*)(pp1 + KS * 8);
            g3 = *(const uint2*)(pp3 + KS * 8);
        } else {
            const int k0 = KS * BK;
#pragma unroll
            for (int j = 0; j < 4; ++j) c1[j] = *(const int4*)(q1 + k0 + j * 4);
#pragma unroll
            for (int j = 0; j < 4; ++j) c3[j] = *(const int4*)(q3 + k0 + j * 4);
        }
        sc1 = s1[sBase + KS]; zz1 = z1[sBase + KS];
        sc3 = s3[sBase + KS]; zz3 = z3[sBase + KS];
    };

    // async-stage A tile KS into buffer bsel (linear LDS, source pre-swizzled)
    auto STAGE_A = [&](int KS, int bsel) {
        const int k0 = KS * BK;
        char* base = smem + bsel * 65536;
#pragma unroll
        for (int i = 0; i < 4; ++i) {
            int blk = wid * 4 + i;                       // 8-row block 0..31
            gload16(aSrc + (size_t)(blk * 8) * HID + k0, base + (blk << 10));
        }
    };

    // dequant B regs -> LDS buffer bsel (XOR chunk swizzle: chunk ^= row&7)
    auto DEQWB = [&](int bsel) {
        u16* dB1 = (u16*)(smem + bsel * 65536 + 32768);
        u16* dB3 = (u16*)(smem + bsel * 65536 + 49152);
        const float of1 = -zz1 * sc1;
        const float of3 = -zz3 * sc3;
        uint4 lo, hi;
        if constexpr (PK) {
            lo = dqw(g1.x, sc1, of1);
            hi = dqw(g1.y, sc1, of1);
        } else {
            lo.x = dq2(c1[0].x, c1[0].y, sc1, of1);
            lo.y = dq2(c1[0].z, c1[0].w, sc1, of1);
            lo.z = dq2(c1[1].x, c1[1].y, sc1, of1);
            lo.w = dq2(c1[1].z, c1[1].w, sc1, of1);
            hi.x = dq2(c1[2].x, c1[2].y, sc1, of1);
            hi.y = dq2(c1[2].z, c1[2].w, sc1, of1);
            hi.z = dq2(c1[3].x, c1[3].y, sc1, of1);
            hi.w = dq2(c1[3].z, c1[3].w, sc1, of1);
        }
        *(uint4*)(&dB1[br * BK + (( bc0      ^ r7) << 3)]) = lo;
        *(uint4*)(&dB1[br * BK + (((bc0 + 1) ^ r7) << 3)]) = hi;
        if constexpr (PK) {
            lo = dqw(g3.x, sc3, of3);
            hi = dqw(g3.y, sc3, of3);
        } else {
            lo.x = dq2(c3[0].x, c3[0].y, sc3, of3);
            lo.y = dq2(c3[0].z, c3[0].w, sc3, of3);
            lo.z = dq2(c3[1].x, c3[1].y, sc3, of3);
            lo.w = dq2(c3[1].z, c3[1].w, sc3, of3);
            hi.x = dq2(c3[2].x, c3[2].y, sc3, of3);
            hi.y = dq2(c3[2].z, c3[2].w, sc3, of3);
            hi.z = dq2(c3[3].x, c3[3].y, sc3, of3);
            hi.w = dq2(c3[3].z, c3[3].w, sc3, of3);
        }
        *(uint4*)(&dB3[br * BK + (( bc0      ^ r7) << 3)]) = lo;
        *(uint4*)(&dB3[br * BK + (((bc0 + 1) ^ r7) << 3)]) = hi;
    };

    const int NK = HID / BK;   // 64

    // prologue: stage tile 0 into buf0
    LOADB(0);
    STAGE_A(0, 0);
    DEQWB(0);
    __syncthreads();

    for (int ks = 0; ks < NK; ++ks) {
        const int nxt = ks + 1 < NK ? ks + 1 : NK - 1;
        const int cur = ks & 1;

        // 1. issue next tile: B codes to regs first, then A DMAs
        LOADB(nxt);
        STAGE_A(nxt, cur ^ 1);

        // 2. MFMA on buf[cur] — next-tile loads land underneath
        const u16* bA  = (const u16*)(smem + cur * 65536);
        const u16* bB1 = (const u16*)(smem + cur * 65536 + 32768);
        const u16* bB3 = (const u16*)(smem + cur * 65536 + 49152);
#pragma unroll
        for (int kk = 0; kk < 2; ++kk) {
            short8 af[4], b1f[4], b3f[4];
#pragma unroll
            for (int m = 0; m < 4; ++m) {
                int row = wr * 64 + m * 16 + fr;
                af[m] = *(const short8*)(&bA[row * BK + ((((kk << 2) | fq) ^ (row & 7)) << 3)]);
            }
#pragma unroll
            for (int n = 0; n < 4; ++n) {
                int row = wc * 64 + n * 16 + fr;
                int ch  = (((kk << 2) | fq) ^ (row & 7)) << 3;
                b1f[n] = *(const short8*)(&bB1[row * BK + ch]);
                b3f[n] = *(const short8*)(&bB3[row * BK + ch]);
            }
#pragma unroll
            for (int m = 0; m < 4; ++m)
#pragma unroll
                for (int n = 0; n < 4; ++n) {
                    accg[m][n] = __builtin_amdgcn_mfma_f32_16x16x32_bf16(af[m], b1f[n], accg[m][n], 0, 0, 0);
                    accu[m][n] = __builtin_amdgcn_mfma_f32_16x16x32_bf16(af[m], b3f[n], accu[m][n], 0, 0, 0);
                }
        }

        // 3. dequant next-tile B -> other buffer
        DEQWB(cur ^ 1);

        // 4. single barrier (drains A DMAs via vmcnt(0) + orders LDS)
        __syncthreads();
    }

    // -- epilogue: silu(g)*u -> swizzled LDS stage -> coalesced stores.
    //    Linear LDS fetch at position cu yields logical chunk cu^(row&7),
    //    which stored at global position cu IS the pre-swizzled hmid layout.
    u16* sO = (u16*)smem;    // [256][128] bf16 = 64 KB
#pragma unroll
    for (int m = 0; m < 4; ++m)
#pragma unroll
        for (int n = 0; n < 4; ++n)
#pragma unroll
            for (int r = 0; r < 4; ++r) {
                int lr = wr * 64 + m * 16 + fq * 4 + r;
                int lc = wc * 64 + n * 16 + fr;
                float g = accg[m][n][r];
                float u = accu[m][n][r];
                float hv = (g / (1.0f + __expf(-g))) * u;
                int cs = ((((lc >> 3) ^ (lr & 7)) << 3) | (lc & 7));
                sO[lr * 128 + cs] = f2b(hv);
            }
    __syncthreads();
#pragma unroll
    for (int it = 0; it < 8; ++it) {
        int idx = it * 512 + tid;          // 16B units, 4096 total
        int row = idx >> 4;
        int cu  = idx & 15;
        uint4 v = ((const uint4*)sO)[row * 16 + cu];
        *(uint4*)(&hout[(size_t)(row0 + row) * INTR + col0 + (cu << 3)]) = v;
    }
}

// ---- kernel 3: down proj --------------------------------------------------

template<bool PK>
__global__ __launch_bounds__(512) void down_kernel(
    const u16* __restrict__ hb,
    const int* __restrict__ w2q, const u32* __restrict__ w2p,
    const float* __restrict__ s2, const float* __restrict__ z2,
    float* __restrict__ out)
{
    __shared__ __align__(16) char smem[98304];   // 2 x (A 32K | B 16K)

    const int tid  = threadIdx.x;
    const int row0 = blockIdx.x * BM;
    const int col0 = blockIdx.y * BN;

    const int l   = tid & 63;
    const int wid = tid >> 6;
    const int wr  = wid >> 1;
    const int wc  = wid & 1;
    const int fq  = l >> 4;
    const int fr  = l & 15;

    f32x4 acc[4][4];
#pragma unroll
    for (int m = 0; m < 4; ++m)
#pragma unroll
        for (int n = 0; n < 4; ++n)
            acc[m][n] = (f32x4){0.f, 0.f, 0.f, 0.f};

    const int br  = tid >> 2;
    const int bc0 = (tid & 3) << 1;
    const int r7  = br & 7;

    const u32* pp2 = w2p + (size_t)(col0 + br) * (INTR / 8) + ((tid & 3) << 1);
    const int* q2 = w2q + (size_t)(col0 + br) * INTR + ((tid & 3) << 4);
    const size_t sBase = (size_t)(col0 + br) * GRP2;

    const u16* aSrc = hb + (size_t)(row0 + (l >> 3)) * INTR + ((l & 7) << 3);

    int4  c2[4];
    uint2 g2;
    float sc, zz;

    auto LOADB = [&](int KS) {
        if constexpr (PK) {
            g2 = *(const uint2*)(pp2 + KS * 8);
        } else {
            const int k0 = KS * BK;
#pragma unroll
            for (int j = 0; j < 4; ++j) c2[j] = *(const int4*)(q2 + k0 + j * 4);
        }
        sc = s2[sBase + KS]; zz = z2[sBase + KS];
    };

    auto STAGE_A = [&](int KS, int bsel) {
        const int k0 = KS * BK;
        char* base = smem + bsel * 49152;
#pragma unroll
        for (int i = 0; i < 4; ++i) {
            int blk = wid * 4 + i;
            gload16(aSrc + (size_t)(blk * 8) * INTR + k0, base + (blk << 10));
        }
    };

    auto DEQWB = [&](int bsel) {
        u16* dB = (u16*)(smem + bsel * 49152 + 32768);
        const float of = -zz * sc;
        uint4 lo, hi;
        if constexpr (PK) {
            lo = dqw(g2.x, sc, of);
            hi = dqw(g2.y, sc, of);
        } else {
            lo.x = dq2(c2[0].x, c2[0].y, sc, of);
            lo.y = dq2(c2[0].z, c2[0].w, sc, of);
            lo.z = dq2(c2[1].x, c2[1].y, sc, of);
            lo.w = dq2(c2[1].z, c2[1].w, sc, of);
            hi.x = dq2(c2[2].x, c2[2].y, sc, of);
            hi.y = dq2(c2[2].z, c2[2].w, sc, of);
            hi.z = dq2(c2[3].x, c2[3].y, sc, of);
            hi.w = dq2(c2[3].z, c2[3].w, sc, of);
        }
        *(uint4*)(&dB[br * BK + (( bc0      ^ r7) << 3)]) = lo;
        *(uint4*)(&dB[br * BK + (((bc0 + 1) ^ r7) << 3)]) = hi;
    };

    const int NK = INTR / BK;   // 224

    LOADB(0);
    STAGE_A(0, 0);
    DEQWB(0);
    __syncthreads();

    for (int ks = 0; ks < NK; ++ks) {
        const int nxt = ks + 1 < NK ? ks + 1 : NK - 1;
        const int cur = ks & 1;

        LOADB(nxt);
        STAGE_A(nxt, cur ^ 1);

        const u16* bA = (const u16*)(smem + cur * 49152);
        const u16* bB = (const u16*)(smem + cur * 49152 + 32768);
#pragma unroll
        for (int kk = 0; kk < 2; ++kk) {
            short8 af[4], bf[4];
#pragma unroll
            for (int m = 0; m < 4; ++m) {
                int row = wr * 64 + m * 16 + fr;
                af[m] = *(const short8*)(&bA[row * BK + ((((kk << 2) | fq) ^ (row & 7)) << 3)]);
            }
#pragma unroll
            for (int n = 0; n < 4; ++n) {
                int row = wc * 64 + n * 16 + fr;
                bf[n] = *(const short8*)(&bB[row * BK + ((((kk << 2) | fq) ^ (row & 7)) << 3)]);
            }
#pragma unroll
            for (int m = 0; m < 4; ++m)
#pragma unroll
                for (int n = 0; n < 4; ++n)
                    acc[m][n] = __builtin_amdgcn_mfma_f32_16x16x32_bf16(af[m], bf[n], acc[m][n], 0, 0, 0);
        }

        DEQWB(cur ^ 1);
        __syncthreads();
    }

    // -- epilogue: swizzled fp32 LDS stage, two 128-row passes (canonical out)
    float* sO = (float*)smem;   // [128][128] f32 = 64 KB
#pragma unroll
    for (int half = 0; half < 2; ++half) {
        if (half) __syncthreads();
        if ((wr >> 1) == half) {
#pragma unroll
            for (int m = 0; m < 4; ++m)
#pragma unroll
                for (int n = 0; n < 4; ++n)
#pragma unroll
                    for (int r = 0; r < 4; ++r) {
                        int lr = (wr & 1) * 64 + m * 16 + fq * 4 + r;
                        int lc = wc * 64 + n * 16 + fr;
                        int cs = ((((lc >> 2) ^ (lr & 7)) << 2) | (lc & 3));
                        sO[lr * 128 + cs] = acc[m][n][r];
                    }
        }
        __syncthreads();
#pragma unroll
        for (int it = 0; it < 8; ++it) {
            int idx = it * 512 + tid;      // 16B units, 4096 total
            int row = idx >> 5;
            int ch  = idx & 31;
            float4 v = ((const float4*)sO)[row * 32 + (ch ^ (row & 7))];
            *(float4*)(&out[(size_t)(row0 + half * 128 + row) * HID + col0 + (ch << 2)]) = v;
        }
    }
}

// ---- launcher --------------------------------------------------------------

extern "C" void kernel_launch(void* const* d_in, const int* in_sizes, int n_in,
                              void* d_out, int out_size, void* d_ws, size_t ws_size,
                              hipStream_t stream) {
    (void)in_sizes; (void)n_in; (void)out_size;

    const float* hs  = (const float*)d_in[0];
    const int*   w1q = (const int*)  d_in[1];
    const float* w1s = (const float*)d_in[2];
    const float* w1z = (const float*)d_in[3];
    const int*   w3q = (const int*)  d_in[4];
    const float* w3s = (const float*)d_in[5];
    const float* w3z = (const float*)d_in[6];
    const int*   w2q = (const int*)  d_in[7];
    const float* w2s = (const float*)d_in[8];
    const float* w2z = (const float*)d_in[9];
    float* out = (float*)d_out;

    const size_t NWRD = (size_t)INTR * HID / 8;   // packed words per weight
    u16* hsb  = (u16*)d_ws;                       // 32 MB  (pre-swizzled bf16)
    u16* hmid = hsb + (size_t)TOK * HID;          // 117 MB (pre-swizzled bf16)
    u32* w1p  = (u32*)(hmid + (size_t)TOK * INTR);
    u32* w3p  = w1p + NWRD;
    u32* w2p  = w3p + NWRD;

    const size_t need = (size_t)TOK * HID * 2 + (size_t)TOK * INTR * 2 + 3 * NWRD * 4;
    const bool pk = ws_size >= need;

    cvt_hs_kernel<<<(TOK * HID / 8) / 256, 256, 0, stream>>>(hs, hsb);

    dim3 g2(TOK / BM, INTR / BN);
    dim3 g3(TOK / BM, HID / BN);

    if (pk) {
        const int pgrid = (int)(NWRD / 256);      // 28672
        pack_kernel<<<pgrid, 256, 0, stream>>>(w1q, w1p);
        pack_kernel<<<pgrid, 256, 0, stream>>>(w3q, w3p);
        pack_kernel<<<pgrid, 256, 0, stream>>>(w2q, w2p);
        gateup_kernel<true><<<g2, 512, 0, stream>>>(hsb, w1q, w1p, w1s, w1z,
                                                    w3q, w3p, w3s, w3z, hmid);
        down_kernel<true><<<g3, 512, 0, stream>>>(hmid, w2q, w2p, w2s, w2z, out);
    } else {
        gateup_kernel<false><<<g2, 512, 0, stream>>>(hsb, w1q, nullptr, w1s, w1z,
                                                     w3q, nullptr, w3s, w3z, hmid);
        down_kernel<false><<<g3, 512, 0, stream>>>(hmid, w2q, nullptr, w2s, w2z, out);
    }
}

// Round 6
// 1514.252 us; speedup vs baseline: 2.8876x; 1.0997x over previous
//
#include <hip/hip_runtime.h>
#include <hip/hip_bf16.h>
#include <stdint.h>

#define HID  4096
#define INTR 14336
#define GS   64
#define TOK  4096
#define GRP1 (HID / GS)    // 64 groups along K for w1/w3
#define GRP2 (INTR / GS)   // 224 groups along K for w2

#define BM 256
#define BN 128
#define BK 64

typedef __attribute__((ext_vector_type(8))) short short8;  // 8 bf16 (4 VGPR)
typedef __attribute__((ext_vector_type(4))) float f32x4;   // MFMA acc
typedef unsigned short u16;
typedef unsigned int   u32;

// ---- helpers -------------------------------------------------------------

__device__ __forceinline__ u16 f2b(float x) {
    return __builtin_bit_cast(u16, __float2bfloat16(x));
}

__device__ __forceinline__ u32 pk2(float a, float b) {
    return (u32)f2b(a) | ((u32)f2b(b) << 16);
}

// dequant two int codes -> packed bf16 pair;  w = c*s + off  (off = -zero*s)
__device__ __forceinline__ u32 dq2(int ca, int cb, float s, float off) {
    return pk2(fmaf((float)ca, s, off), fmaf((float)cb, s, off));
}

// dequant 8 codes packed in one u32 -> 4 packed bf16 pairs
__device__ __forceinline__ uint4 dqw(u32 w, float s, float off) {
    uint4 v;
    v.x = dq2((int)( w        & 15), (int)((w >>  4) & 15), s, off);
    v.y = dq2((int)((w >>  8) & 15), (int)((w >> 12) & 15), s, off);
    v.z = dq2((int)((w >> 16) & 15), (int)((w >> 20) & 15), s, off);
    v.w = dq2((int)((w >> 24) & 15), (int)( w >> 28       ), s, off);
    return v;
}

// async global -> LDS, 16 bytes/lane, linear LDS dest (wave-uniform base + lane*16)
__device__ __forceinline__ void gload16(const void* g, void* l) {
    __builtin_amdgcn_global_load_lds(
        (const __attribute__((address_space(1))) void*)g,
        (__attribute__((address_space(3))) void*)l, 16, 0, 0);
}

// ---- weight dequant pass: int32 codes -> bf16, PRE-SWIZZLED ---------------
// one thread = one 8-elem (16B) chunk. Within each row's 64-elem K-group,
// chunk c is stored at position (c & ~7) | ((c&7) ^ (row&7)) so that the
// GEMM's linear global_load_lds + swizzled ds_read sees the canonical data.

__global__ void dqw_kernel(const int* __restrict__ q, const float* __restrict__ s,
                           const float* __restrict__ z, u16* __restrict__ o, int cols) {
    int c = blockIdx.x * blockDim.x + threadIdx.x;   // chunk index within row
    int r = blockIdx.y;                              // row
    int grp = cols >> 6;
    const int* src = q + (size_t)r * cols + ((size_t)c << 3);
    int4 a = *(const int4*)src;
    int4 b = *(const int4*)(src + 4);
    float sc = s[(size_t)r * grp + (c >> 3)];
    float zz = z[(size_t)r * grp + (c >> 3)];
    float of = -zz * sc;
    uint4 v;
    v.x = dq2(a.x, a.y, sc, of);
    v.y = dq2(a.z, a.w, sc, of);
    v.z = dq2(b.x, b.y, sc, of);
    v.w = dq2(b.z, b.w, sc, of);
    int cs = (c & ~7) | ((c & 7) ^ (r & 7));
    *(uint4*)(o + (size_t)r * cols + ((size_t)cs << 3)) = v;
}

// ---- repack (fallback path): int32 codes -> 8x 4-bit nibbles per u32 ------

__global__ void pack_kernel(const int* __restrict__ q, u32* __restrict__ p) {
    int i = blockIdx.x * blockDim.x + threadIdx.x;
    const int4* s = (const int4*)q + (size_t)i * 2;
    int4 a = s[0], b = s[1];
    u32 w = (u32)(a.x & 15)        | ((u32)(a.y & 15) << 4)
          | ((u32)(a.z & 15) << 8) | ((u32)(a.w & 15) << 12)
          | ((u32)(b.x & 15) << 16)| ((u32)(b.y & 15) << 20)
          | ((u32)(b.z & 15) << 24)| ((u32)(b.w & 15) << 28);
    p[i] = w;
}

// ---- kernel 1: hs fp32 -> bf16, PRE-SWIZZLED ------------------------------

__global__ void cvt_hs_kernel(const float* __restrict__ x, u16* __restrict__ y) {
    int i = blockIdx.x * blockDim.x + threadIdx.x;   // one 8-elem chunk
    int t = i >> 9;            // HID/8 = 512 chunks per row
    int c = i & 511;
    const float4* xp = (const float4*)x + (size_t)i * 2;
    float4 a = xp[0], b = xp[1];
    uint4 o;
    o.x = pk2(a.x, a.y); o.y = pk2(a.z, a.w);
    o.z = pk2(b.x, b.y); o.w = pk2(b.z, b.w);
    int cs = (c & ~7) | ((c & 7) ^ (t & 7));
    ((uint4*)y)[(size_t)t * 512 + cs] = o;
}

// ---- kernel 2: fused gate+up dual GEMM + SiLU*mul -------------------------
// MODE 0: A and B staged via global_load_lds from pre-swizzled bf16 (no VALU
//         dequant in the loop). MODE 1: B dequanted from packed nibbles.
//         Double-buffered LDS, one barrier per K-step.

template<int MODE>
__global__ __launch_bounds__(512) void gateup_kernel(
    const u16* __restrict__ hsb,
    const u16* __restrict__ w1b, const u16* __restrict__ w3b,
    const u32* __restrict__ w1p, const u32* __restrict__ w3p,
    const float* __restrict__ s1, const float* __restrict__ z1,
    const float* __restrict__ s3, const float* __restrict__ z3,
    u16* __restrict__ hout)
{
    __shared__ __align__(16) char smem[131072];   // 2 x (A 32K | B1 16K | B3 16K)

    const int tid  = threadIdx.x;
    const int row0 = blockIdx.x * BM;
    const int col0 = blockIdx.y * BN;

    const int l   = tid & 63;
    const int wid = tid >> 6;      // 0..7
    const int wr  = wid >> 1;      // 0..3 (M)
    const int wc  = wid & 1;       // 0..1 (N)
    const int fq  = l >> 4;        // 0..3
    const int fr  = l & 15;        // 0..15

    f32x4 accg[4][4];
    f32x4 accu[4][4];
#pragma unroll
    for (int m = 0; m < 4; ++m)
#pragma unroll
        for (int n = 0; n < 4; ++n) {
            accg[m][n] = (f32x4){0.f, 0.f, 0.f, 0.f};
            accu[m][n] = (f32x4){0.f, 0.f, 0.f, 0.f};
        }

    // A staging source: lane covers row (blk*8 + l>>3), chunk (l&7)
    const u16* aSrc = hsb + (size_t)(row0 + (l >> 3)) * HID + ((l & 7) << 3);
    // B staging sources (MODE 0)
    const u16* b1Src = w1b + (size_t)(col0 + (l >> 3)) * HID + ((l & 7) << 3);
    const u16* b3Src = w3b + (size_t)(col0 + (l >> 3)) * HID + ((l & 7) << 3);

    // MODE 1 state
    const int br  = tid >> 2;
    const int bc0 = (tid & 3) << 1;
    const int r7  = br & 7;
    const u32* pp1 = w1p + (size_t)(col0 + br) * (HID / 8) + ((tid & 3) << 1);
    const u32* pp3 = w3p + (size_t)(col0 + br) * (HID / 8) + ((tid & 3) << 1);
    const size_t sBase = (size_t)(col0 + br) * GRP1;
    uint2 g1, g3;
    float sc1, zz1, sc3, zz3;

    auto LOADB = [&](int KS) {
        g1 = *(const uint2*)(pp1 + KS * 8);
        g3 = *(const uint2*)(pp3 + KS * 8);
        sc1 = s1[sBase + KS]; zz1 = z1[sBase + KS];
        sc3 = s3[sBase + KS]; zz3 = z3[sBase + KS];
    };

    auto STAGE_A = [&](int KS, int bsel) {
        const int k0 = KS * BK;
        char* base = smem + bsel * 65536;
#pragma unroll
        for (int i = 0; i < 4; ++i) {
            int blk = wid * 4 + i;                       // 8-row block 0..31
            gload16(aSrc + (size_t)(blk * 8) * HID + k0, base + (blk << 10));
        }
    };

    auto STAGE_B = [&](int KS, int bsel) {
        const int k0 = KS * BK;
        char* base = smem + bsel * 65536;
#pragma unroll
        for (int i = 0; i < 2; ++i) {
            int blk = wid * 2 + i;                       // 8-row block 0..15
            gload16(b1Src + (size_t)(blk * 8) * HID + k0, base + 32768 + (blk << 10));
            gload16(b3Src + (size_t)(blk * 8) * HID + k0, base + 49152 + (blk << 10));
        }
    };

    auto DEQWB = [&](int bsel) {
        u16* dB1 = (u16*)(smem + bsel * 65536 + 32768);
        u16* dB3 = (u16*)(smem + bsel * 65536 + 49152);
        const float of1 = -zz1 * sc1;
        const float of3 = -zz3 * sc3;
        uint4 lo, hi;
        lo = dqw(g1.x, sc1, of1);
        hi = dqw(g1.y, sc1, of1);
        *(uint4*)(&dB1[br * BK + (( bc0      ^ r7) << 3)]) = lo;
        *(uint4*)(&dB1[br * BK + (((bc0 + 1) ^ r7) << 3)]) = hi;
        lo = dqw(g3.x, sc3, of3);
        hi = dqw(g3.y, sc3, of3);
        *(uint4*)(&dB3[br * BK + (( bc0      ^ r7) << 3)]) = lo;
        *(uint4*)(&dB3[br * BK + (((bc0 + 1) ^ r7) << 3)]) = hi;
    };

    const int NK = HID / BK;   // 64

    // prologue
    if constexpr (MODE == 0) {
        STAGE_A(0, 0);
        STAGE_B(0, 0);
    } else {
        LOADB(0);
        STAGE_A(0, 0);
        DEQWB(0);
    }
    __syncthreads();

    for (int ks = 0; ks < NK; ++ks) {
        const int nxt = ks + 1 < NK ? ks + 1 : NK - 1;
        const int cur = ks & 1;

        // 1. issue next tile's staging
        if constexpr (MODE == 0) {
            STAGE_A(nxt, cur ^ 1);
            STAGE_B(nxt, cur ^ 1);
        } else {
            LOADB(nxt);
            STAGE_A(nxt, cur ^ 1);
        }

        // 2. MFMA on buf[cur] — staging lands underneath
        const u16* bA  = (const u16*)(smem + cur * 65536);
        const u16* bB1 = (const u16*)(smem + cur * 65536 + 32768);
        const u16* bB3 = (const u16*)(smem + cur * 65536 + 49152);
#pragma unroll
        for (int kk = 0; kk < 2; ++kk) {
            short8 af[4], b1f[4], b3f[4];
#pragma unroll
            for (int m = 0; m < 4; ++m) {
                int row = wr * 64 + m * 16 + fr;
                af[m] = *(const short8*)(&bA[row * BK + ((((kk << 2) | fq) ^ (row & 7)) << 3)]);
            }
#pragma unroll
            for (int n = 0; n < 4; ++n) {
                int row = wc * 64 + n * 16 + fr;
                int ch  = (((kk << 2) | fq) ^ (row & 7)) << 3;
                b1f[n] = *(const short8*)(&bB1[row * BK + ch]);
                b3f[n] = *(const short8*)(&bB3[row * BK + ch]);
            }
#pragma unroll
            for (int m = 0; m < 4; ++m)
#pragma unroll
                for (int n = 0; n < 4; ++n) {
                    accg[m][n] = __builtin_amdgcn_mfma_f32_16x16x32_bf16(af[m], b1f[n], accg[m][n], 0, 0, 0);
                    accu[m][n] = __builtin_amdgcn_mfma_f32_16x16x32_bf16(af[m], b3f[n], accu[m][n], 0, 0, 0);
                }
        }

        // 3. (MODE 1) dequant next-tile B -> other buffer
        if constexpr (MODE == 1) DEQWB(cur ^ 1);

        // 4. single barrier (drains DMAs via vmcnt(0) + orders LDS)
        __syncthreads();
    }

    // -- epilogue: silu(g)*u -> swizzled LDS stage -> coalesced stores.
    //    Linear LDS fetch at position cu stored at global position cu
    //    reproduces the pre-swizzled hmid layout the down kernel expects.
    u16* sO = (u16*)smem;    // [256][128] bf16 = 64 KB
#pragma unroll
    for (int m = 0; m < 4; ++m)
#pragma unroll
        for (int n = 0; n < 4; ++n)
#pragma unroll
            for (int r = 0; r < 4; ++r) {
                int lr = wr * 64 + m * 16 + fq * 4 + r;
                int lc = wc * 64 + n * 16 + fr;
                float g = accg[m][n][r];
                float u = accu[m][n][r];
                float hv = (g / (1.0f + __expf(-g))) * u;
                int cs = ((((lc >> 3) ^ (lr & 7)) << 3) | (lc & 7));
                sO[lr * 128 + cs] = f2b(hv);
            }
    __syncthreads();
#pragma unroll
    for (int it = 0; it < 8; ++it) {
        int idx = it * 512 + tid;          // 16B units, 4096 total
        int row = idx >> 4;
        int cu  = idx & 15;
        uint4 v = ((const uint4*)sO)[row * 16 + cu];
        *(uint4*)(&hout[(size_t)(row0 + row) * INTR + col0 + (cu << 3)]) = v;
    }
}

// ---- kernel 3: down proj --------------------------------------------------

template<int MODE>
__global__ __launch_bounds__(512) void down_kernel(
    const u16* __restrict__ hb,
    const u16* __restrict__ w2b, const u32* __restrict__ w2p,
    const float* __restrict__ s2, const float* __restrict__ z2,
    float* __restrict__ out)
{
    __shared__ __align__(16) char smem[98304];   // 2 x (A 32K | B 16K)

    const int tid  = threadIdx.x;
    const int row0 = blockIdx.x * BM;
    const int col0 = blockIdx.y * BN;

    const int l   = tid & 63;
    const int wid = tid >> 6;
    const int wr  = wid >> 1;
    const int wc  = wid & 1;
    const int fq  = l >> 4;
    const int fr  = l & 15;

    f32x4 acc[4][4];
#pragma unroll
    for (int m = 0; m < 4; ++m)
#pragma unroll
        for (int n = 0; n < 4; ++n)
            acc[m][n] = (f32x4){0.f, 0.f, 0.f, 0.f};

    const u16* aSrc = hb + (size_t)(row0 + (l >> 3)) * INTR + ((l & 7) << 3);
    const u16* bSrc = w2b + (size_t)(col0 + (l >> 3)) * INTR + ((l & 7) << 3);

    const int br  = tid >> 2;
    const int bc0 = (tid & 3) << 1;
    const int r7  = br & 7;
    const u32* pp2 = w2p + (size_t)(col0 + br) * (INTR / 8) + ((tid & 3) << 1);
    const size_t sBase = (size_t)(col0 + br) * GRP2;
    uint2 g2;
    float sc, zz;

    auto LOADB = [&](int KS) {
        g2 = *(const uint2*)(pp2 + KS * 8);
        sc = s2[sBase + KS]; zz = z2[sBase + KS];
    };

    auto STAGE_A = [&](int KS, int bsel) {
        const int k0 = KS * BK;
        char* base = smem + bsel * 49152;
#pragma unroll
        for (int i = 0; i < 4; ++i) {
            int blk = wid * 4 + i;
            gload16(aSrc + (size_t)(blk * 8) * INTR + k0, base + (blk << 10));
        }
    };

    auto STAGE_B = [&](int KS, int bsel) {
        const int k0 = KS * BK;
        char* base = smem + bsel * 49152;
#pragma unroll
        for (int i = 0; i < 2; ++i) {
            int blk = wid * 2 + i;
            gload16(bSrc + (size_t)(blk * 8) * INTR + k0, base + 32768 + (blk << 10));
        }
    };

    auto DEQWB = [&](int bsel) {
        u16* dB = (u16*)(smem + bsel * 49152 + 32768);
        const float of = -zz * sc;
        uint4 lo, hi;
        lo = dqw(g2.x, sc, of);
        hi = dqw(g2.y, sc, of);
        *(uint4*)(&dB[br * BK + (( bc0      ^ r7) << 3)]) = lo;
        *(uint4*)(&dB[br * BK + (((bc0 + 1) ^ r7) << 3)]) = hi;
    };

    const int NK = INTR / BK;   // 224

    if constexpr (MODE == 0) {
        STAGE_A(0, 0);
        STAGE_B(0, 0);
    } else {
        LOADB(0);
        STAGE_A(0, 0);
        DEQWB(0);
    }
    __syncthreads();

    for (int ks = 0; ks < NK; ++ks) {
        const int nxt = ks + 1 < NK ? ks + 1 : NK - 1;
        const int cur = ks & 1;

        if constexpr (MODE == 0) {
            STAGE_A(nxt, cur ^ 1);
            STAGE_B(nxt, cur ^ 1);
        } else {
            LOADB(nxt);
            STAGE_A(nxt, cur ^ 1);
        }

        const u16* bA = (const u16*)(smem + cur * 49152);
        const u16* bB = (const u16*)(smem + cur * 49152 + 32768);
#pragma unroll
        for (int kk = 0; kk < 2; ++kk) {
            short8 af[4], bf[4];
#pragma unroll
            for (int m = 0; m < 4; ++m) {
                int row = wr * 64 + m * 16 + fr;
                af[m] = *(const short8*)(&bA[row * BK + ((((kk << 2) | fq) ^ (row & 7)) << 3)]);
            }
#pragma unroll
            for (int n = 0; n < 4; ++n) {
                int row = wc * 64 + n * 16 + fr;
                bf[n] = *(const short8*)(&bB[row * BK + ((((kk << 2) | fq) ^ (row & 7)) << 3)]);
            }
#pragma unroll
            for (int m = 0; m < 4; ++m)
#pragma unroll
                for (int n = 0; n < 4; ++n)
                    acc[m][n] = __builtin_amdgcn_mfma_f32_16x16x32_bf16(af[m], bf[n], acc[m][n], 0, 0, 0);
        }

        if constexpr (MODE == 1) DEQWB(cur ^ 1);
        __syncthreads();
    }

    // -- epilogue: swizzled fp32 LDS stage, two 128-row passes (canonical out)
    float* sO = (float*)smem;   // [128][128] f32 = 64 KB
#pragma unroll
    for (int half = 0; half < 2; ++half) {
        if (half) __syncthreads();
        if ((wr >> 1) == half) {
#pragma unroll
            for (int m = 0; m < 4; ++m)
#pragma unroll
                for (int n = 0; n < 4; ++n)
#pragma unroll
                    for (int r = 0; r < 4; ++r) {
                        int lr = (wr & 1) * 64 + m * 16 + fq * 4 + r;
                        int lc = wc * 64 + n * 16 + fr;
                        int cs = ((((lc >> 2) ^ (lr & 7)) << 2) | (lc & 3));
                        sO[lr * 128 + cs] = acc[m][n][r];
                    }
        }
        __syncthreads();
#pragma unroll
        for (int it = 0; it < 8; ++it) {
            int idx = it * 512 + tid;      // 16B units, 4096 total
            int row = idx >> 5;
            int ch  = idx & 31;
            float4 v = ((const float4*)sO)[row * 32 + (ch ^ (row & 7))];
            *(float4*)(&out[(size_t)(row0 + half * 128 + row) * HID + col0 + (ch << 2)]) = v;
        }
    }
}

// ---- launcher --------------------------------------------------------------

extern "C" void kernel_launch(void* const* d_in, const int* in_sizes, int n_in,
                              void* d_out, int out_size, void* d_ws, size_t ws_size,
                              hipStream_t stream) {
    (void)in_sizes; (void)n_in; (void)out_size;

    const float* hs  = (const float*)d_in[0];
    const int*   w1q = (const int*)  d_in[1];
    const float* w1s = (const float*)d_in[2];
    const float* w1z = (const float*)d_in[3];
    const int*   w3q = (const int*)  d_in[4];
    const float* w3s = (const float*)d_in[5];
    const float* w3z = (const float*)d_in[6];
    const int*   w2q = (const int*)  d_in[7];
    const float* w2s = (const float*)d_in[8];
    const float* w2z = (const float*)d_in[9];
    float* out = (float*)d_out;

    const size_t NWRD  = (size_t)INTR * HID / 8;   // packed words per weight
    const size_t SZ_HSB  = (size_t)TOK * HID;      // elems
    const size_t SZ_HMID = (size_t)TOK * INTR;
    const size_t SZ_WB   = (size_t)INTR * HID;

    u16* hsb  = (u16*)d_ws;                        // 32 MB  (pre-swizzled bf16)
    u16* hmid = hsb + SZ_HSB;                      // 117 MB (pre-swizzled bf16)
    u16* wb1  = hmid + SZ_HMID;                    // 117 MB (w1 bf16; later w2 bf16)
    u16* wb3  = wb1 + SZ_WB;                       // 117 MB (w3 bf16)
    // fallback packed-code pointers (alias the wb region)
    u32* w1p  = (u32*)wb1;
    u32* w3p  = w1p + NWRD;
    u32* w2p  = w3p + NWRD;

    const size_t needF = (SZ_HSB + SZ_HMID + 2 * SZ_WB) * 2;
    const size_t needP = (SZ_HSB + SZ_HMID) * 2 + 3 * NWRD * 4;

    cvt_hs_kernel<<<(TOK * HID / 8) / 256, 256, 0, stream>>>(hs, hsb);

    dim3 g2(TOK / BM, INTR / BN);
    dim3 g3(TOK / BM, HID / BN);

    if (ws_size >= needF) {
        // full pre-dequant path: pure bf16 GEMMs, DMA-staged A and B
        dqw_kernel<<<dim3(HID / 8 / 256, INTR), 256, 0, stream>>>(w1q, w1s, w1z, wb1, HID);
        dqw_kernel<<<dim3(HID / 8 / 256, INTR), 256, 0, stream>>>(w3q, w3s, w3z, wb3, HID);
        gateup_kernel<0><<<g2, 512, 0, stream>>>(hsb, wb1, wb3, nullptr, nullptr,
                                                 nullptr, nullptr, nullptr, nullptr, hmid);
        // w2 dequant AFTER gateup: aliases wb1's region (stream-ordered)
        dqw_kernel<<<dim3(INTR / 8 / 256, HID), 256, 0, stream>>>(w2q, w2s, w2z, wb1, INTR);
        down_kernel<0><<<g3, 512, 0, stream>>>(hmid, wb1, nullptr, nullptr, nullptr, out);
    } else if (ws_size >= needP) {
        const int pgrid = (int)(NWRD / 256);
        pack_kernel<<<pgrid, 256, 0, stream>>>(w1q, w1p);
        pack_kernel<<<pgrid, 256, 0, stream>>>(w3q, w3p);
        pack_kernel<<<pgrid, 256, 0, stream>>>(w2q, w2p);
        gateup_kernel<1><<<g2, 512, 0, stream>>>(hsb, nullptr, nullptr, w1p, w3p,
                                                 w1s, w1z, w3s, w3z, hmid);
        down_kernel<1><<<g3, 512, 0, stream>>>(hmid, nullptr, w2p, w2s, w2z, out);
    }
}

// Round 7
// 1457.195 us; speedup vs baseline: 3.0006x; 1.0392x over previous
//
#include <hip/hip_runtime.h>
#include <hip/hip_bf16.h>
#include <stdint.h>

#define HID  4096
#define INTR 14336
#define GS   64
#define TOK  4096
#define GRP1 (HID / GS)    // 64 groups along K for w1/w3
#define GRP2 (INTR / GS)   // 224 groups along K for w2

#define BK 64

typedef __attribute__((ext_vector_type(8)))  short short8;  // 8 bf16 (4 VGPR)
typedef __attribute__((ext_vector_type(16))) float f32x16;  // 32x32 MFMA acc
typedef unsigned short u16;
typedef unsigned int   u32;

// ---- helpers -------------------------------------------------------------

__device__ __forceinline__ u16 f2b(float x) {
    return __builtin_bit_cast(u16, __float2bfloat16(x));
}

__device__ __forceinline__ u32 pk2(float a, float b) {
    return (u32)f2b(a) | ((u32)f2b(b) << 16);
}

// dequant two int codes -> packed bf16 pair;  w = c*s + off  (off = -zero*s)
__device__ __forceinline__ u32 dq2(int ca, int cb, float s, float off) {
    return pk2(fmaf((float)ca, s, off), fmaf((float)cb, s, off));
}

// dequant 8 codes packed in one u32 -> 4 packed bf16 pairs (one 16B chunk)
__device__ __forceinline__ uint4 dqw(u32 w, float s, float off) {
    uint4 v;
    v.x = dq2((int)( w        & 15), (int)((w >>  4) & 15), s, off);
    v.y = dq2((int)((w >>  8) & 15), (int)((w >> 12) & 15), s, off);
    v.z = dq2((int)((w >> 16) & 15), (int)((w >> 20) & 15), s, off);
    v.w = dq2((int)((w >> 24) & 15), (int)( w >> 28       ), s, off);
    return v;
}

// async global -> LDS, 16 bytes/lane, linear LDS dest (wave-uniform base + lane*16)
__device__ __forceinline__ void gload16(const void* g, void* l) {
    __builtin_amdgcn_global_load_lds(
        (const __attribute__((address_space(1))) void*)g,
        (__attribute__((address_space(3))) void*)l, 16, 0, 0);
}

// ---- weight dequant pass: int32 codes -> bf16, PRE-SWIZZLED ---------------

__global__ void dqw_kernel(const int* __restrict__ q, const float* __restrict__ s,
                           const float* __restrict__ z, u16* __restrict__ o, int cols) {
    int c = blockIdx.x * blockDim.x + threadIdx.x;   // chunk index within row
    int r = blockIdx.y;                              // row
    int grp = cols >> 6;
    const int* src = q + (size_t)r * cols + ((size_t)c << 3);
    int4 a = *(const int4*)src;
    int4 b = *(const int4*)(src + 4);
    float sc = s[(size_t)r * grp + (c >> 3)];
    float zz = z[(size_t)r * grp + (c >> 3)];
    float of = -zz * sc;
    uint4 v;
    v.x = dq2(a.x, a.y, sc, of);
    v.y = dq2(a.z, a.w, sc, of);
    v.z = dq2(b.x, b.y, sc, of);
    v.w = dq2(b.z, b.w, sc, of);
    int cs = (c & ~7) | ((c & 7) ^ (r & 7));
    *(uint4*)(o + (size_t)r * cols + ((size_t)cs << 3)) = v;
}

// ---- repack (fallback path): int32 codes -> 8x 4-bit nibbles per u32 ------

__global__ void pack_kernel(const int* __restrict__ q, u32* __restrict__ p) {
    int i = blockIdx.x * blockDim.x + threadIdx.x;
    const int4* s = (const int4*)q + (size_t)i * 2;
    int4 a = s[0], b = s[1];
    u32 w = (u32)(a.x & 15)        | ((u32)(a.y & 15) << 4)
          | ((u32)(a.z & 15) << 8) | ((u32)(a.w & 15) << 12)
          | ((u32)(b.x & 15) << 16)| ((u32)(b.y & 15) << 20)
          | ((u32)(b.z & 15) << 24)| ((u32)(b.w & 15) << 28);
    p[i] = w;
}

// ---- kernel 1: hs fp32 -> bf16, PRE-SWIZZLED ------------------------------

__global__ void cvt_hs_kernel(const float* __restrict__ x, u16* __restrict__ y) {
    int i = blockIdx.x * blockDim.x + threadIdx.x;   // one 8-elem chunk
    int t = i >> 9;            // HID/8 = 512 chunks per row
    int c = i & 511;
    const float4* xp = (const float4*)x + (size_t)i * 2;
    float4 a = xp[0], b = xp[1];
    uint4 o;
    o.x = pk2(a.x, a.y); o.y = pk2(a.z, a.w);
    o.z = pk2(b.x, b.y); o.w = pk2(b.z, b.w);
    int cs = (c & ~7) | ((c & 7) ^ (t & 7));
    ((uint4*)y)[(size_t)t * 512 + cs] = o;
}

// ---- kernel 2: fused gate+up dual GEMM + SiLU*mul -------------------------
// BM=256 BN=128 BK=64, 8 waves (4M x 2N), wave tile 64x64, 32x32x16 MFMA.
// MODE 0: A and B staged via global_load_lds from pre-swizzled bf16.
// MODE 1: B dequanted from packed nibbles. Double-buffered, 1 barrier/step.

template<int MODE>
__global__ __launch_bounds__(512) void gateup_kernel(
    const u16* __restrict__ hsb,
    const u16* __restrict__ w1b, const u16* __restrict__ w3b,
    const u32* __restrict__ w1p, const u32* __restrict__ w3p,
    const float* __restrict__ s1, const float* __restrict__ z1,
    const float* __restrict__ s3, const float* __restrict__ z3,
    u16* __restrict__ hout)
{
    __shared__ __align__(16) char smem[131072];   // 2 x (A 32K | B1 16K | B3 16K)

    const int tid  = threadIdx.x;
    const int row0 = blockIdx.x * 256;
    const int col0 = blockIdx.y * 128;

    const int l   = tid & 63;
    const int wid = tid >> 6;      // 0..7
    const int wr  = wid >> 1;      // 0..3 (M, 64 rows each)
    const int wc  = wid & 1;       // 0..1 (N, 64 cols each)
    const int l31 = l & 31;
    const int lh  = l >> 5;        // 0/1 : k-half of the fragment

    f32x16 accg[2][2];
    f32x16 accu[2][2];
#pragma unroll
    for (int m = 0; m < 2; ++m)
#pragma unroll
        for (int n = 0; n < 2; ++n) {
#pragma unroll
            for (int i = 0; i < 16; ++i) { accg[m][n][i] = 0.f; accu[m][n][i] = 0.f; }
        }

    // A staging source: lane covers row (blk*8 + l>>3), chunk (l&7)
    const u16* aSrc = hsb + (size_t)(row0 + (l >> 3)) * HID + ((l & 7) << 3);
    const u16* b1Src = w1b + (size_t)(col0 + (l >> 3)) * HID + ((l & 7) << 3);
    const u16* b3Src = w3b + (size_t)(col0 + (l >> 3)) * HID + ((l & 7) << 3);

    // MODE 1 state
    const int br  = tid >> 2;
    const int bc0 = (tid & 3) << 1;
    const int r7  = br & 7;
    const u32* pp1 = w1p + (size_t)(col0 + br) * (HID / 8) + ((tid & 3) << 1);
    const u32* pp3 = w3p + (size_t)(col0 + br) * (HID / 8) + ((tid & 3) << 1);
    const size_t sBase = (size_t)(col0 + br) * GRP1;
    uint2 g1, g3;
    float sc1, zz1, sc3, zz3;

    auto LOADB = [&](int KS) {
        g1 = *(const uint2*)(pp1 + KS * 8);
        g3 = *(const uint2*)(pp3 + KS * 8);
        sc1 = s1[sBase + KS]; zz1 = z1[sBase + KS];
        sc3 = s3[sBase + KS]; zz3 = z3[sBase + KS];
    };

    auto STAGE_A = [&](int KS, int bsel) {
        const int k0 = KS * BK;
        char* base = smem + bsel * 65536;
#pragma unroll
        for (int i = 0; i < 4; ++i) {
            int blk = wid * 4 + i;                       // 8-row block 0..31
            gload16(aSrc + (size_t)(blk * 8) * HID + k0, base + (blk << 10));
        }
    };

    auto STAGE_B = [&](int KS, int bsel) {
        const int k0 = KS * BK;
        char* base = smem + bsel * 65536;
#pragma unroll
        for (int i = 0; i < 2; ++i) {
            int blk = wid * 2 + i;                       // 8-row block 0..15
            gload16(b1Src + (size_t)(blk * 8) * HID + k0, base + 32768 + (blk << 10));
            gload16(b3Src + (size_t)(blk * 8) * HID + k0, base + 49152 + (blk << 10));
        }
    };

    auto DEQWB = [&](int bsel) {
        u16* dB1 = (u16*)(smem + bsel * 65536 + 32768);
        u16* dB3 = (u16*)(smem + bsel * 65536 + 49152);
        const float of1 = -zz1 * sc1;
        const float of3 = -zz3 * sc3;
        uint4 lo, hi;
        lo = dqw(g1.x, sc1, of1);
        hi = dqw(g1.y, sc1, of1);
        *(uint4*)(&dB1[br * BK + (( bc0      ^ r7) << 3)]) = lo;
        *(uint4*)(&dB1[br * BK + (((bc0 + 1) ^ r7) << 3)]) = hi;
        lo = dqw(g3.x, sc3, of3);
        hi = dqw(g3.y, sc3, of3);
        *(uint4*)(&dB3[br * BK + (( bc0      ^ r7) << 3)]) = lo;
        *(uint4*)(&dB3[br * BK + (((bc0 + 1) ^ r7) << 3)]) = hi;
    };

    const int NK = HID / BK;   // 64

    if constexpr (MODE == 0) {
        STAGE_A(0, 0);
        STAGE_B(0, 0);
    } else {
        LOADB(0);
        STAGE_A(0, 0);
        DEQWB(0);
    }
    __syncthreads();

    for (int ks = 0; ks < NK; ++ks) {
        const int nxt = ks + 1 < NK ? ks + 1 : NK - 1;
        const int cur = ks & 1;

        if constexpr (MODE == 0) {
            STAGE_A(nxt, cur ^ 1);
            STAGE_B(nxt, cur ^ 1);
        } else {
            LOADB(nxt);
            STAGE_A(nxt, cur ^ 1);
        }

        const u16* bA  = (const u16*)(smem + cur * 65536);
        const u16* bB1 = (const u16*)(smem + cur * 65536 + 32768);
        const u16* bB3 = (const u16*)(smem + cur * 65536 + 49152);

        __builtin_amdgcn_s_setprio(1);
#pragma unroll
        for (int kslice = 0; kslice < 4; ++kslice) {
            const int cb = kslice * 2 + lh;              // logical 16B chunk 0..7
            short8 af[2], b1f[2], b3f[2];
#pragma unroll
            for (int m = 0; m < 2; ++m) {
                int row = wr * 64 + m * 32 + l31;
                af[m] = *(const short8*)(&bA[row * BK + ((cb ^ (row & 7)) << 3)]);
            }
#pragma unroll
            for (int n = 0; n < 2; ++n) {
                int row = wc * 64 + n * 32 + l31;
                int ch  = (cb ^ (row & 7)) << 3;
                b1f[n] = *(const short8*)(&bB1[row * BK + ch]);
                b3f[n] = *(const short8*)(&bB3[row * BK + ch]);
            }
#pragma unroll
            for (int m = 0; m < 2; ++m)
#pragma unroll
                for (int n = 0; n < 2; ++n) {
                    accg[m][n] = __builtin_amdgcn_mfma_f32_32x32x16_bf16(af[m], b1f[n], accg[m][n], 0, 0, 0);
                    accu[m][n] = __builtin_amdgcn_mfma_f32_32x32x16_bf16(af[m], b3f[n], accu[m][n], 0, 0, 0);
                }
        }
        __builtin_amdgcn_s_setprio(0);

        if constexpr (MODE == 1) DEQWB(cur ^ 1);
        __syncthreads();
    }

    // -- epilogue: silu(g)*u -> swizzled LDS stage -> coalesced stores.
    //    (C/D map: col = l&31, row = (reg&3) + 8*(reg>>2) + 4*(l>>5))
    u16* sO = (u16*)smem;    // [256][128] bf16 = 64 KB
#pragma unroll
    for (int m = 0; m < 2; ++m)
#pragma unroll
        for (int n = 0; n < 2; ++n)
#pragma unroll
            for (int r = 0; r < 16; ++r) {
                int lr = wr * 64 + m * 32 + ((r & 3) + 8 * (r >> 2) + 4 * lh);
                int lc = wc * 64 + n * 32 + l31;
                float g = accg[m][n][r];
                float u = accu[m][n][r];
                float hv = (g / (1.0f + __expf(-g))) * u;
                int cs = ((((lc >> 3) ^ (lr & 7)) << 3) | (lc & 7));
                sO[lr * 128 + cs] = f2b(hv);
            }
    __syncthreads();
#pragma unroll
    for (int it = 0; it < 8; ++it) {
        int idx = it * 512 + tid;          // 16B units, 4096 total
        int row = idx >> 4;
        int cu  = idx & 15;
        uint4 v = ((const uint4*)sO)[row * 16 + cu];
        *(uint4*)(&hout[(size_t)(row0 + row) * INTR + col0 + (cu << 3)]) = v;
    }
}

// ---- kernel 3: down proj --------------------------------------------------
// BM=256 BN=256 BK=64, 8 waves (2M x 4N), wave tile 128x64, 32x32x16 MFMA.

template<int MODE>
__global__ __launch_bounds__(512) void down_kernel(
    const u16* __restrict__ hb,
    const u16* __restrict__ w2b, const u32* __restrict__ w2p,
    const float* __restrict__ s2, const float* __restrict__ z2,
    float* __restrict__ out)
{
    __shared__ __align__(16) char smem[131072];   // 2 x (A 32K | B 32K)

    const int tid  = threadIdx.x;
    const int row0 = blockIdx.x * 256;
    const int col0 = blockIdx.y * 256;

    const int l   = tid & 63;
    const int wid = tid >> 6;
    const int wr  = wid >> 2;      // 0..1 (M, 128 rows each)
    const int wc  = wid & 3;       // 0..3 (N, 64 cols each)
    const int l31 = l & 31;
    const int lh  = l >> 5;

    f32x16 acc[4][2];
#pragma unroll
    for (int m = 0; m < 4; ++m)
#pragma unroll
        for (int n = 0; n < 2; ++n)
#pragma unroll
            for (int i = 0; i < 16; ++i) acc[m][n][i] = 0.f;

    const u16* aSrc = hb  + (size_t)(row0 + (l >> 3)) * INTR + ((l & 7) << 3);
    const u16* bSrc = w2b + (size_t)(col0 + (l >> 3)) * INTR + ((l & 7) << 3);

    // MODE 1 state: B tile 256 rows x 64 K; 2 threads/row, 4 chunks each
    const int br  = tid >> 1;              // 0..255
    const int bc0 = (tid & 1) << 2;        // 0 or 4
    const int r7  = br & 7;
    const u32* pp2 = w2p + (size_t)(col0 + br) * (INTR / 8) + bc0;
    const size_t sBase = (size_t)(col0 + br) * GRP2;
    uint4 g2d;
    float sc, zz;

    auto LOADB = [&](int KS) {
        g2d = *(const uint4*)(pp2 + KS * 8);
        sc = s2[sBase + KS]; zz = z2[sBase + KS];
    };

    auto STAGE_A = [&](int KS, int bsel) {
        const int k0 = KS * BK;
        char* base = smem + bsel * 65536;
#pragma unroll
        for (int i = 0; i < 4; ++i) {
            int blk = wid * 4 + i;
            gload16(aSrc + (size_t)(blk * 8) * INTR + k0, base + (blk << 10));
        }
    };

    auto STAGE_B = [&](int KS, int bsel) {
        const int k0 = KS * BK;
        char* base = smem + bsel * 65536;
#pragma unroll
        for (int i = 0; i < 4; ++i) {
            int blk = wid * 4 + i;
            gload16(bSrc + (size_t)(blk * 8) * INTR + k0, base + 32768 + (blk << 10));
        }
    };

    auto DEQWB = [&](int bsel) {
        u16* dB = (u16*)(smem + bsel * 65536 + 32768);
        const float of = -zz * sc;
        uint4 v;
        v = dqw(g2d.x, sc, of);
        *(uint4*)(&dB[br * BK + (((bc0 + 0) ^ r7) << 3)]) = v;
        v = dqw(g2d.y, sc, of);
        *(uint4*)(&dB[br * BK + (((bc0 + 1) ^ r7) << 3)]) = v;
        v = dqw(g2d.z, sc, of);
        *(uint4*)(&dB[br * BK + (((bc0 + 2) ^ r7) << 3)]) = v;
        v = dqw(g2d.w, sc, of);
        *(uint4*)(&dB[br * BK + (((bc0 + 3) ^ r7) << 3)]) = v;
    };

    const int NK = INTR / BK;   // 224

    if constexpr (MODE == 0) {
        STAGE_A(0, 0);
        STAGE_B(0, 0);
    } else {
        LOADB(0);
        STAGE_A(0, 0);
        DEQWB(0);
    }
    __syncthreads();

    for (int ks = 0; ks < NK; ++ks) {
        const int nxt = ks + 1 < NK ? ks + 1 : NK - 1;
        const int cur = ks & 1;

        if constexpr (MODE == 0) {
            STAGE_A(nxt, cur ^ 1);
            STAGE_B(nxt, cur ^ 1);
        } else {
            LOADB(nxt);
            STAGE_A(nxt, cur ^ 1);
        }

        const u16* bA = (const u16*)(smem + cur * 65536);
        const u16* bB = (const u16*)(smem + cur * 65536 + 32768);

        __builtin_amdgcn_s_setprio(1);
#pragma unroll
        for (int kslice = 0; kslice < 4; ++kslice) {
            const int cb = kslice * 2 + lh;
            short8 af[4], bf[2];
#pragma unroll
            for (int m = 0; m < 4; ++m) {
                int row = wr * 128 + m * 32 + l31;
                af[m] = *(const short8*)(&bA[row * BK + ((cb ^ (row & 7)) << 3)]);
            }
#pragma unroll
            for (int n = 0; n < 2; ++n) {
                int row = wc * 64 + n * 32 + l31;
                bf[n] = *(const short8*)(&bB[row * BK + ((cb ^ (row & 7)) << 3)]);
            }
#pragma unroll
            for (int m = 0; m < 4; ++m)
#pragma unroll
                for (int n = 0; n < 2; ++n)
                    acc[m][n] = __builtin_amdgcn_mfma_f32_32x32x16_bf16(af[m], bf[n], acc[m][n], 0, 0, 0);
        }
        __builtin_amdgcn_s_setprio(0);

        if constexpr (MODE == 1) DEQWB(cur ^ 1);
        __syncthreads();
    }

    // -- epilogue: swizzled fp32 LDS stage, two 128-row passes --
    float* sO = (float*)smem;   // [128][256] f32 = 128 KB
#pragma unroll
    for (int half = 0; half < 2; ++half) {
        if (half) __syncthreads();
        if (wr == half) {
#pragma unroll
            for (int m = 0; m < 4; ++m)
#pragma unroll
                for (int n = 0; n < 2; ++n)
#pragma unroll
                    for (int r = 0; r < 16; ++r) {
                        int lr = m * 32 + ((r & 3) + 8 * (r >> 2) + 4 * lh);  // 0..127
                        int lc = wc * 64 + n * 32 + l31;                      // 0..255
                        int cs = ((((lc >> 2) ^ (lr & 7)) << 2) | (lc & 3));
                        sO[lr * 256 + cs] = acc[m][n][r];
                    }
        }
        __syncthreads();
#pragma unroll
        for (int it = 0; it < 16; ++it) {
            int idx = it * 512 + tid;      // 16B units, 8192 total
            int row = idx >> 6;            // 64 float4 per row
            int ch  = idx & 63;
            float4 v = ((const float4*)sO)[row * 64 + (ch ^ (row & 7))];
            *(float4*)(&out[(size_t)(row0 + half * 128 + row) * HID + col0 + (ch << 2)]) = v;
        }
    }
}

// ---- launcher --------------------------------------------------------------

extern "C" void kernel_launch(void* const* d_in, const int* in_sizes, int n_in,
                              void* d_out, int out_size, void* d_ws, size_t ws_size,
                              hipStream_t stream) {
    (void)in_sizes; (void)n_in; (void)out_size;

    const float* hs  = (const float*)d_in[0];
    const int*   w1q = (const int*)  d_in[1];
    const float* w1s = (const float*)d_in[2];
    const float* w1z = (const float*)d_in[3];
    const int*   w3q = (const int*)  d_in[4];
    const float* w3s = (const float*)d_in[5];
    const float* w3z = (const float*)d_in[6];
    const int*   w2q = (const int*)  d_in[7];
    const float* w2s = (const float*)d_in[8];
    const float* w2z = (const float*)d_in[9];
    float* out = (float*)d_out;

    const size_t NWRD  = (size_t)INTR * HID / 8;   // packed words per weight
    const size_t SZ_HSB  = (size_t)TOK * HID;
    const size_t SZ_HMID = (size_t)TOK * INTR;
    const size_t SZ_WB   = (size_t)INTR * HID;

    u16* hsb  = (u16*)d_ws;                        // 33 MB  (pre-swizzled bf16)
    u16* hmid = hsb + SZ_HSB;                      // 117 MB (pre-swizzled bf16)
    u16* wb1  = hmid + SZ_HMID;                    // 117 MB (w1 bf16; later w2 bf16)
    u16* wb3  = wb1 + SZ_WB;                       // 117 MB (w3 bf16)
    u32* w1p  = (u32*)wb1;                         // fallback aliases
    u32* w3p  = w1p + NWRD;
    u32* w2p  = w3p + NWRD;

    const size_t needF = (SZ_HSB + SZ_HMID + 2 * SZ_WB) * 2;
    const size_t needP = (SZ_HSB + SZ_HMID) * 2 + 3 * NWRD * 4;

    cvt_hs_kernel<<<(TOK * HID / 8) / 256, 256, 0, stream>>>(hs, hsb);

    dim3 g2(TOK / 256, INTR / 128);
    dim3 g3(TOK / 256, HID / 256);

    if (ws_size >= needF) {
        dqw_kernel<<<dim3(HID / 8 / 256, INTR), 256, 0, stream>>>(w1q, w1s, w1z, wb1, HID);
        dqw_kernel<<<dim3(HID / 8 / 256, INTR), 256, 0, stream>>>(w3q, w3s, w3z, wb3, HID);
        gateup_kernel<0><<<g2, 512, 0, stream>>>(hsb, wb1, wb3, nullptr, nullptr,
                                                 nullptr, nullptr, nullptr, nullptr, hmid);
        dqw_kernel<<<dim3(INTR / 8 / 256, HID), 256, 0, stream>>>(w2q, w2s, w2z, wb1, INTR);
        down_kernel<0><<<g3, 512, 0, stream>>>(hmid, wb1, nullptr, nullptr, nullptr, out);
    } else if (ws_size >= needP) {
        const int pgrid = (int)(NWRD / 256);
        pack_kernel<<<pgrid, 256, 0, stream>>>(w1q, w1p);
        pack_kernel<<<pgrid, 256, 0, stream>>>(w3q, w3p);
        pack_kernel<<<pgrid, 256, 0, stream>>>(w2q, w2p);
        gateup_kernel<1><<<g2, 512, 0, stream>>>(hsb, nullptr, nullptr, w1p, w3p,
                                                 w1s, w1z, w3s, w3z, hmid);
        down_kernel<1><<<g3, 512, 0, stream>>>(hmid, nullptr, w2p, w2s, w2z, out);
    }
}

// Round 8
// 1354.774 us; speedup vs baseline: 3.2275x; 1.0756x over previous
//
#include <hip/hip_runtime.h>
#include <hip/hip_bf16.h>
#include <stdint.h>

#define HID  4096
#define INTR 14336
#define GS   64
#define TOK  4096
#define GRP1 (HID / GS)    // 64 groups along K for w1/w3
#define GRP2 (INTR / GS)   // 224 groups along K for w2

#define BK 64

typedef __attribute__((ext_vector_type(8))) short short8;  // 8 bf16 (4 VGPR)
typedef __attribute__((ext_vector_type(4))) float f32x4;   // 16x16 MFMA acc
typedef unsigned short u16;
typedef unsigned int   u32;

// ---- helpers -------------------------------------------------------------

__device__ __forceinline__ u16 f2b(float x) {
    return __builtin_bit_cast(u16, __float2bfloat16(x));
}

__device__ __forceinline__ u32 pk2(float a, float b) {
    return (u32)f2b(a) | ((u32)f2b(b) << 16);
}

// dequant two int codes -> packed bf16 pair;  w = c*s + off  (off = -zero*s)
__device__ __forceinline__ u32 dq2(int ca, int cb, float s, float off) {
    return pk2(fmaf((float)ca, s, off), fmaf((float)cb, s, off));
}

// dequant 8 codes packed in one u32 -> 4 packed bf16 pairs (one 16B chunk)
__device__ __forceinline__ uint4 dqw(u32 w, float s, float off) {
    uint4 v;
    v.x = dq2((int)( w        & 15), (int)((w >>  4) & 15), s, off);
    v.y = dq2((int)((w >>  8) & 15), (int)((w >> 12) & 15), s, off);
    v.z = dq2((int)((w >> 16) & 15), (int)((w >> 20) & 15), s, off);
    v.w = dq2((int)((w >> 24) & 15), (int)( w >> 28       ), s, off);
    return v;
}

// async global -> LDS, 16 bytes/lane, linear LDS dest (wave-uniform base + lane*16)
__device__ __forceinline__ void gload16(const void* g, void* l) {
    __builtin_amdgcn_global_load_lds(
        (const __attribute__((address_space(1))) void*)g,
        (__attribute__((address_space(3))) void*)l, 16, 0, 0);
}

// ---- weight dequant pass: int32 codes -> bf16, PRE-SWIZZLED ---------------

__global__ void dqw_kernel(const int* __restrict__ q, const float* __restrict__ s,
                           const float* __restrict__ z, u16* __restrict__ o, int cols) {
    int c = blockIdx.x * blockDim.x + threadIdx.x;   // chunk index within row
    int r = blockIdx.y;                              // row
    int grp = cols >> 6;
    const int* src = q + (size_t)r * cols + ((size_t)c << 3);
    int4 a = *(const int4*)src;
    int4 b = *(const int4*)(src + 4);
    float sc = s[(size_t)r * grp + (c >> 3)];
    float zz = z[(size_t)r * grp + (c >> 3)];
    float of = -zz * sc;
    uint4 v;
    v.x = dq2(a.x, a.y, sc, of);
    v.y = dq2(a.z, a.w, sc, of);
    v.z = dq2(b.x, b.y, sc, of);
    v.w = dq2(b.z, b.w, sc, of);
    int cs = (c & ~7) | ((c & 7) ^ (r & 7));
    *(uint4*)(o + (size_t)r * cols + ((size_t)cs << 3)) = v;
}

// ---- repack (fallback path): int32 codes -> 8x 4-bit nibbles per u32 ------

__global__ void pack_kernel(const int* __restrict__ q, u32* __restrict__ p) {
    int i = blockIdx.x * blockDim.x + threadIdx.x;
    const int4* s = (const int4*)q + (size_t)i * 2;
    int4 a = s[0], b = s[1];
    u32 w = (u32)(a.x & 15)        | ((u32)(a.y & 15) << 4)
          | ((u32)(a.z & 15) << 8) | ((u32)(a.w & 15) << 12)
          | ((u32)(b.x & 15) << 16)| ((u32)(b.y & 15) << 20)
          | ((u32)(b.z & 15) << 24)| ((u32)(b.w & 15) << 28);
    p[i] = w;
}

// ---- kernel 1: hs fp32 -> bf16, PRE-SWIZZLED ------------------------------

__global__ void cvt_hs_kernel(const float* __restrict__ x, u16* __restrict__ y) {
    int i = blockIdx.x * blockDim.x + threadIdx.x;   // one 8-elem chunk
    int t = i >> 9;            // HID/8 = 512 chunks per row
    int c = i & 511;
    const float4* xp = (const float4*)x + (size_t)i * 2;
    float4 a = xp[0], b = xp[1];
    uint4 o;
    o.x = pk2(a.x, a.y); o.y = pk2(a.z, a.w);
    o.z = pk2(b.x, b.y); o.w = pk2(b.z, b.w);
    int cs = (c & ~7) | ((c & 7) ^ (t & 7));
    ((uint4*)y)[(size_t)t * 512 + cs] = o;
}

// ---- kernel 2: fused gate+up dual GEMM + SiLU*mul -------------------------
// BM=256 BN=128 BK=64, 8 waves (4M x 2N), wave tile 64x64, 16x16x32 MFMA
// (conflict-free fragment pattern: 16 rows x 4 chunk positions per wave).
// MODE 0: A and B staged via global_load_lds from pre-swizzled bf16.
// MODE 1: B dequanted from packed nibbles. Double-buffered, 1 barrier/step.

template<int MODE>
__global__ __launch_bounds__(512) void gateup_kernel(
    const u16* __restrict__ hsb,
    const u16* __restrict__ w1b, const u16* __restrict__ w3b,
    const u32* __restrict__ w1p, const u32* __restrict__ w3p,
    const float* __restrict__ s1, const float* __restrict__ z1,
    const float* __restrict__ s3, const float* __restrict__ z3,
    u16* __restrict__ hout)
{
    __shared__ __align__(16) char smem[131072];   // 2 x (A 32K | B1 16K | B3 16K)

    const int tid  = threadIdx.x;
    const int row0 = blockIdx.x * 256;
    const int col0 = blockIdx.y * 128;

    const int l   = tid & 63;
    const int wid = tid >> 6;      // 0..7
    const int wr  = wid >> 1;      // 0..3 (M)
    const int wc  = wid & 1;       // 0..1 (N)
    const int fq  = l >> 4;        // 0..3
    const int fr  = l & 15;        // 0..15

    f32x4 accg[4][4];
    f32x4 accu[4][4];
#pragma unroll
    for (int m = 0; m < 4; ++m)
#pragma unroll
        for (int n = 0; n < 4; ++n) {
            accg[m][n] = (f32x4){0.f, 0.f, 0.f, 0.f};
            accu[m][n] = (f32x4){0.f, 0.f, 0.f, 0.f};
        }

    // A staging source: lane covers row (blk*8 + l>>3), chunk (l&7)
    const u16* aSrc  = hsb + (size_t)(row0 + (l >> 3)) * HID + ((l & 7) << 3);
    const u16* b1Src = w1b + (size_t)(col0 + (l >> 3)) * HID + ((l & 7) << 3);
    const u16* b3Src = w3b + (size_t)(col0 + (l >> 3)) * HID + ((l & 7) << 3);

    // MODE 1 state
    const int br  = tid >> 2;
    const int bc0 = (tid & 3) << 1;
    const int r7  = br & 7;
    const u32* pp1 = w1p + (size_t)(col0 + br) * (HID / 8) + ((tid & 3) << 1);
    const u32* pp3 = w3p + (size_t)(col0 + br) * (HID / 8) + ((tid & 3) << 1);
    const size_t sBase = (size_t)(col0 + br) * GRP1;
    uint2 g1, g3;
    float sc1, zz1, sc3, zz3;

    auto LOADB = [&](int KS) {
        g1 = *(const uint2*)(pp1 + KS * 8);
        g3 = *(const uint2*)(pp3 + KS * 8);
        sc1 = s1[sBase + KS]; zz1 = z1[sBase + KS];
        sc3 = s3[sBase + KS]; zz3 = z3[sBase + KS];
    };

    auto STAGE_A = [&](int KS, int bsel) {
        const int k0 = KS * BK;
        char* base = smem + bsel * 65536;
#pragma unroll
        for (int i = 0; i < 4; ++i) {
            int blk = wid * 4 + i;                       // 8-row block 0..31
            gload16(aSrc + (size_t)(blk * 8) * HID + k0, base + (blk << 10));
        }
    };

    auto STAGE_B = [&](int KS, int bsel) {
        const int k0 = KS * BK;
        char* base = smem + bsel * 65536;
#pragma unroll
        for (int i = 0; i < 2; ++i) {
            int blk = wid * 2 + i;                       // 8-row block 0..15
            gload16(b1Src + (size_t)(blk * 8) * HID + k0, base + 32768 + (blk << 10));
            gload16(b3Src + (size_t)(blk * 8) * HID + k0, base + 49152 + (blk << 10));
        }
    };

    auto DEQWB = [&](int bsel) {
        u16* dB1 = (u16*)(smem + bsel * 65536 + 32768);
        u16* dB3 = (u16*)(smem + bsel * 65536 + 49152);
        const float of1 = -zz1 * sc1;
        const float of3 = -zz3 * sc3;
        uint4 lo, hi;
        lo = dqw(g1.x, sc1, of1);
        hi = dqw(g1.y, sc1, of1);
        *(uint4*)(&dB1[br * BK + (( bc0      ^ r7) << 3)]) = lo;
        *(uint4*)(&dB1[br * BK + (((bc0 + 1) ^ r7) << 3)]) = hi;
        lo = dqw(g3.x, sc3, of3);
        hi = dqw(g3.y, sc3, of3);
        *(uint4*)(&dB3[br * BK + (( bc0      ^ r7) << 3)]) = lo;
        *(uint4*)(&dB3[br * BK + (((bc0 + 1) ^ r7) << 3)]) = hi;
    };

    const int NK = HID / BK;   // 64

    if constexpr (MODE == 0) {
        STAGE_A(0, 0);
        STAGE_B(0, 0);
    } else {
        LOADB(0);
        STAGE_A(0, 0);
        DEQWB(0);
    }
    __syncthreads();

    for (int ks = 0; ks < NK; ++ks) {
        const int nxt = ks + 1 < NK ? ks + 1 : NK - 1;
        const int cur = ks & 1;

        if constexpr (MODE == 0) {
            STAGE_A(nxt, cur ^ 1);
            STAGE_B(nxt, cur ^ 1);
        } else {
            LOADB(nxt);
            STAGE_A(nxt, cur ^ 1);
        }

        const u16* bA  = (const u16*)(smem + cur * 65536);
        const u16* bB1 = (const u16*)(smem + cur * 65536 + 32768);
        const u16* bB3 = (const u16*)(smem + cur * 65536 + 49152);

        __builtin_amdgcn_s_setprio(1);
#pragma unroll
        for (int kk = 0; kk < 2; ++kk) {
            short8 af[4], b1f[4], b3f[4];
#pragma unroll
            for (int m = 0; m < 4; ++m) {
                int row = wr * 64 + m * 16 + fr;
                af[m] = *(const short8*)(&bA[row * BK + ((((kk << 2) | fq) ^ (row & 7)) << 3)]);
            }
#pragma unroll
            for (int n = 0; n < 4; ++n) {
                int row = wc * 64 + n * 16 + fr;
                int ch  = (((kk << 2) | fq) ^ (row & 7)) << 3;
                b1f[n] = *(const short8*)(&bB1[row * BK + ch]);
                b3f[n] = *(const short8*)(&bB3[row * BK + ch]);
            }
#pragma unroll
            for (int m = 0; m < 4; ++m)
#pragma unroll
                for (int n = 0; n < 4; ++n) {
                    accg[m][n] = __builtin_amdgcn_mfma_f32_16x16x32_bf16(af[m], b1f[n], accg[m][n], 0, 0, 0);
                    accu[m][n] = __builtin_amdgcn_mfma_f32_16x16x32_bf16(af[m], b3f[n], accu[m][n], 0, 0, 0);
                }
        }
        __builtin_amdgcn_s_setprio(0);

        if constexpr (MODE == 1) DEQWB(cur ^ 1);
        __syncthreads();
    }

    // -- epilogue: silu(g)*u -> swizzled LDS stage -> coalesced stores.
    u16* sO = (u16*)smem;    // [256][128] bf16 = 64 KB
#pragma unroll
    for (int m = 0; m < 4; ++m)
#pragma unroll
        for (int n = 0; n < 4; ++n)
#pragma unroll
            for (int r = 0; r < 4; ++r) {
                int lr = wr * 64 + m * 16 + fq * 4 + r;
                int lc = wc * 64 + n * 16 + fr;
                float g = accg[m][n][r];
                float u = accu[m][n][r];
                float hv = (g / (1.0f + __expf(-g))) * u;
                int cs = ((((lc >> 3) ^ (lr & 7)) << 3) | (lc & 7));
                sO[lr * 128 + cs] = f2b(hv);
            }
    __syncthreads();
#pragma unroll
    for (int it = 0; it < 8; ++it) {
        int idx = it * 512 + tid;          // 16B units, 4096 total
        int row = idx >> 4;
        int cu  = idx & 15;
        uint4 v = ((const uint4*)sO)[row * 16 + cu];
        *(uint4*)(&hout[(size_t)(row0 + row) * INTR + col0 + (cu << 3)]) = v;
    }
}

// ---- kernel 3: down proj --------------------------------------------------
// BM=256 BN=256 BK=64, 8 waves (2M x 4N), wave tile 128x64, 16x16x32 MFMA.

template<int MODE>
__global__ __launch_bounds__(512) void down_kernel(
    const u16* __restrict__ hb,
    const u16* __restrict__ w2b, const u32* __restrict__ w2p,
    const float* __restrict__ s2, const float* __restrict__ z2,
    float* __restrict__ out)
{
    __shared__ __align__(16) char smem[131072];   // 2 x (A 32K | B 32K)

    const int tid  = threadIdx.x;
    const int row0 = blockIdx.x * 256;
    const int col0 = blockIdx.y * 256;

    const int l   = tid & 63;
    const int wid = tid >> 6;
    const int wr  = wid >> 2;      // 0..1 (M, 128 rows each)
    const int wc  = wid & 3;       // 0..3 (N, 64 cols each)
    const int fq  = l >> 4;
    const int fr  = l & 15;

    f32x4 acc[8][4];
#pragma unroll
    for (int m = 0; m < 8; ++m)
#pragma unroll
        for (int n = 0; n < 4; ++n)
            acc[m][n] = (f32x4){0.f, 0.f, 0.f, 0.f};

    const u16* aSrc = hb  + (size_t)(row0 + (l >> 3)) * INTR + ((l & 7) << 3);
    const u16* bSrc = w2b + (size_t)(col0 + (l >> 3)) * INTR + ((l & 7) << 3);

    // MODE 1 state: B tile 256 rows x 64 K; 2 threads/row, 4 chunks each
    const int br  = tid >> 1;              // 0..255
    const int bc0 = (tid & 1) << 2;        // 0 or 4
    const int r7  = br & 7;
    const u32* pp2 = w2p + (size_t)(col0 + br) * (INTR / 8) + bc0;
    const size_t sBase = (size_t)(col0 + br) * GRP2;
    uint4 g2d;
    float sc, zz;

    auto LOADB = [&](int KS) {
        g2d = *(const uint4*)(pp2 + KS * 8);
        sc = s2[sBase + KS]; zz = z2[sBase + KS];
    };

    auto STAGE_A = [&](int KS, int bsel) {
        const int k0 = KS * BK;
        char* base = smem + bsel * 65536;
#pragma unroll
        for (int i = 0; i < 4; ++i) {
            int blk = wid * 4 + i;
            gload16(aSrc + (size_t)(blk * 8) * INTR + k0, base + (blk << 10));
        }
    };

    auto STAGE_B = [&](int KS, int bsel) {
        const int k0 = KS * BK;
        char* base = smem + bsel * 65536;
#pragma unroll
        for (int i = 0; i < 4; ++i) {
            int blk = wid * 4 + i;
            gload16(bSrc + (size_t)(blk * 8) * INTR + k0, base + 32768 + (blk << 10));
        }
    };

    auto DEQWB = [&](int bsel) {
        u16* dB = (u16*)(smem + bsel * 65536 + 32768);
        const float of = -zz * sc;
        uint4 v;
        v = dqw(g2d.x, sc, of);
        *(uint4*)(&dB[br * BK + (((bc0 + 0) ^ r7) << 3)]) = v;
        v = dqw(g2d.y, sc, of);
        *(uint4*)(&dB[br * BK + (((bc0 + 1) ^ r7) << 3)]) = v;
        v = dqw(g2d.z, sc, of);
        *(uint4*)(&dB[br * BK + (((bc0 + 2) ^ r7) << 3)]) = v;
        v = dqw(g2d.w, sc, of);
        *(uint4*)(&dB[br * BK + (((bc0 + 3) ^ r7) << 3)]) = v;
    };

    const int NK = INTR / BK;   // 224

    if constexpr (MODE == 0) {
        STAGE_A(0, 0);
        STAGE_B(0, 0);
    } else {
        LOADB(0);
        STAGE_A(0, 0);
        DEQWB(0);
    }
    __syncthreads();

    for (int ks = 0; ks < NK; ++ks) {
        const int nxt = ks + 1 < NK ? ks + 1 : NK - 1;
        const int cur = ks & 1;

        if constexpr (MODE == 0) {
            STAGE_A(nxt, cur ^ 1);
            STAGE_B(nxt, cur ^ 1);
        } else {
            LOADB(nxt);
            STAGE_A(nxt, cur ^ 1);
        }

        const u16* bA = (const u16*)(smem + cur * 65536);
        const u16* bB = (const u16*)(smem + cur * 65536 + 32768);

        __builtin_amdgcn_s_setprio(1);
#pragma unroll
        for (int kk = 0; kk < 2; ++kk) {
            short8 af[8], bf[4];
#pragma unroll
            for (int m = 0; m < 8; ++m) {
                int row = wr * 128 + m * 16 + fr;
                af[m] = *(const short8*)(&bA[row * BK + ((((kk << 2) | fq) ^ (row & 7)) << 3)]);
            }
#pragma unroll
            for (int n = 0; n < 4; ++n) {
                int row = wc * 64 + n * 16 + fr;
                bf[n] = *(const short8*)(&bB[row * BK + ((((kk << 2) | fq) ^ (row & 7)) << 3)]);
            }
#pragma unroll
            for (int m = 0; m < 8; ++m)
#pragma unroll
                for (int n = 0; n < 4; ++n)
                    acc[m][n] = __builtin_amdgcn_mfma_f32_16x16x32_bf16(af[m], bf[n], acc[m][n], 0, 0, 0);
        }
        __builtin_amdgcn_s_setprio(0);

        if constexpr (MODE == 1) DEQWB(cur ^ 1);
        __syncthreads();
    }

    // -- epilogue: swizzled fp32 LDS stage, two 128-row passes --
    float* sO = (float*)smem;   // [128][256] f32 = 128 KB
#pragma unroll
    for (int half = 0; half < 2; ++half) {
        if (half) __syncthreads();
        if (wr == half) {
#pragma unroll
            for (int m = 0; m < 8; ++m)
#pragma unroll
                for (int n = 0; n < 4; ++n)
#pragma unroll
                    for (int r = 0; r < 4; ++r) {
                        int lr = m * 16 + fq * 4 + r;            // 0..127
                        int lc = wc * 64 + n * 16 + fr;          // 0..255
                        int cs = ((((lc >> 2) ^ (lr & 7)) << 2) | (lc & 3));
                        sO[lr * 256 + cs] = acc[m][n][r];
                    }
        }
        __syncthreads();
#pragma unroll
        for (int it = 0; it < 16; ++it) {
            int idx = it * 512 + tid;      // 16B units, 8192 total
            int row = idx >> 6;            // 64 float4 per row
            int ch  = idx & 63;
            float4 v = ((const float4*)sO)[row * 64 + (ch ^ (row & 7))];
            *(float4*)(&out[(size_t)(row0 + half * 128 + row) * HID + col0 + (ch << 2)]) = v;
        }
    }
}

// ---- launcher --------------------------------------------------------------

extern "C" void kernel_launch(void* const* d_in, const int* in_sizes, int n_in,
                              void* d_out, int out_size, void* d_ws, size_t ws_size,
                              hipStream_t stream) {
    (void)in_sizes; (void)n_in; (void)out_size;

    const float* hs  = (const float*)d_in[0];
    const int*   w1q = (const int*)  d_in[1];
    const float* w1s = (const float*)d_in[2];
    const float* w1z = (const float*)d_in[3];
    const int*   w3q = (const int*)  d_in[4];
    const float* w3s = (const float*)d_in[5];
    const float* w3z = (const float*)d_in[6];
    const int*   w2q = (const int*)  d_in[7];
    const float* w2s = (const float*)d_in[8];
    const float* w2z = (const float*)d_in[9];
    float* out = (float*)d_out;

    const size_t NWRD  = (size_t)INTR * HID / 8;   // packed words per weight
    const size_t SZ_HSB  = (size_t)TOK * HID;
    const size_t SZ_HMID = (size_t)TOK * INTR;
    const size_t SZ_WB   = (size_t)INTR * HID;

    u16* hsb  = (u16*)d_ws;                        // 33 MB  (pre-swizzled bf16)
    u16* hmid = hsb + SZ_HSB;                      // 117 MB (pre-swizzled bf16)
    u16* wb1  = hmid + SZ_HMID;                    // 117 MB (w1 bf16; later w2 bf16)
    u16* wb3  = wb1 + SZ_WB;                       // 117 MB (w3 bf16)
    u32* w1p  = (u32*)wb1;                         // fallback aliases
    u32* w3p  = w1p + NWRD;
    u32* w2p  = w3p + NWRD;

    const size_t needF = (SZ_HSB + SZ_HMID + 2 * SZ_WB) * 2;
    const size_t needP = (SZ_HSB + SZ_HMID) * 2 + 3 * NWRD * 4;

    cvt_hs_kernel<<<(TOK * HID / 8) / 256, 256, 0, stream>>>(hs, hsb);

    dim3 g2(TOK / 256, INTR / 128);
    dim3 g3(TOK / 256, HID / 256);

    if (ws_size >= needF) {
        dqw_kernel<<<dim3(HID / 8 / 256, INTR), 256, 0, stream>>>(w1q, w1s, w1z, wb1, HID);
        dqw_kernel<<<dim3(HID / 8 / 256, INTR), 256, 0, stream>>>(w3q, w3s, w3z, wb3, HID);
        gateup_kernel<0><<<g2, 512, 0, stream>>>(hsb, wb1, wb3, nullptr, nullptr,
                                                 nullptr, nullptr, nullptr, nullptr, hmid);
        dqw_kernel<<<dim3(INTR / 8 / 256, HID), 256, 0, stream>>>(w2q, w2s, w2z, wb1, INTR);
        down_kernel<0><<<g3, 512, 0, stream>>>(hmid, wb1, nullptr, nullptr, nullptr, out);
    } else if (ws_size >= needP) {
        const int pgrid = (int)(NWRD / 256);
        pack_kernel<<<pgrid, 256, 0, stream>>>(w1q, w1p);
        pack_kernel<<<pgrid, 256, 0, stream>>>(w3q, w3p);
        pack_kernel<<<pgrid, 256, 0, stream>>>(w2q, w2p);
        gateup_kernel<1><<<g2, 512, 0, stream>>>(hsb, nullptr, nullptr, w1p, w3p,
                                                 w1s, w1z, w3s, w3z, hmid);
        down_kernel<1><<<g3, 512, 0, stream>>>(hmid, nullptr, w2p, w2s, w2z, out);
    }
}